// Round 19
// baseline (189.786 us; speedup 1.0000x reference)
//
#include <hip/hip_runtime.h>
#include <math.h>

typedef unsigned short ush;
typedef short bf16x8 __attribute__((ext_vector_type(8)));
typedef float f32x4 __attribute__((ext_vector_type(4)));
typedef ush ushx8 __attribute__((ext_vector_type(8)));

// ---------- bf16 helpers ----------
__device__ __forceinline__ ush f2bf(float f) {
    unsigned u = __float_as_uint(f);
    u += 0x7FFFu + ((u >> 16) & 1u);
    return (ush)(u >> 16);
}
__device__ __forceinline__ float bf2f(ush u) {
    return __uint_as_float((unsigned)u << 16);
}

// 128 buckets of 512 dsts; pack: src (17b) | (d & 511) << 17
#define SRC_MASK 0x1FFFF

// ================= fused A: hist (blocks 0..255) + prep_w (blocks 256..279) ====
__global__ __launch_bounds__(256) void fusedA_k(
    const int* __restrict__ dsts, int* __restrict__ ghist,
    const float* __restrict__ Wl1, const float* __restrict__ Wr1,
    const float* __restrict__ Wl2, const float* __restrict__ Wr2,
    ush* __restrict__ wph, ush* __restrict__ wpl, int e0, int etot) {
    const int t = threadIdx.x;
    if (blockIdx.x < 256) {
        __shared__ int h[128];
        if (t < 128) h[t] = 0;
        __syncthreads();
        for (int i = blockIdx.x * 256 + t; i < etot; i += 256 * 256) {
            const int d = (i < e0) ? dsts[i] : (i - e0);
            atomicAdd(&h[d >> 9], 1);
        }
        __syncthreads();
        if (t < 128 && h[t]) atomicAdd(&ghist[t], h[t]);
    } else {
        const int bid = (blockIdx.x - 256) * 4 + (t >> 6);
        const int l = t & 63;
        const float* W;
        int C, fid;
        if (bid < 32)      { W = Wl1; C = 128; fid = bid; }
        else if (bid < 64) { W = Wr1; C = 128; fid = bid - 32; }
        else if (bid < 80) { W = Wl2; C = 64;  fid = bid - 64; }
        else               { W = Wr2; C = 64;  fid = bid - 80; }
        const int nc16 = C / 16;
        const int ks = fid / nc16, c16 = fid % nc16;
#pragma unroll
        for (int j = 0; j < 8; ++j) {
            const int k = ks * 32 + (l >> 4) * 8 + j;
            const int c = c16 * 16 + (l & 15);
            const float v = W[(size_t)k * C + c];
            const ush h = f2bf(v);
            wph[(size_t)(bid * 64 + l) * 8 + j] = h;
            wpl[(size_t)(bid * 64 + l) * 8 + j] = f2bf(v - bf2f(h));
        }
    }
}

// ================= fused B: semisort (blocks < nblka) + gemm1 (rest) ==========
__global__ __launch_bounds__(256) void fusedB_k(
    const int* __restrict__ srcs, const int* __restrict__ dsts,
    const int* __restrict__ ghist, int* __restrict__ cur, int* __restrict__ pairs,
    const float* __restrict__ x,
    const ush* __restrict__ wh1, const ush* __restrict__ wl1,
    const ush* __restrict__ wh2, const ush* __restrict__ wl2,
    ush* __restrict__ ybf, float* __restrict__ yf,
    int e0, int etot, int nblka, int n) {
    const int t = threadIdx.x;
    if ((int)blockIdx.x < nblka) {
        __shared__ int sb[128];
        __shared__ int red[128];
        __shared__ int hist[128], gbase[128], lcur[128];
        if (t < 128) red[t] = ghist[t];
        __syncthreads();
#pragma unroll
        for (int s = 1; s < 128; s <<= 1) {
            const int add = (t < 128 && t >= s) ? red[t - s] : 0;
            __syncthreads();
            if (t < 128) red[t] += add;
            __syncthreads();
        }
        if (t < 128) {
            sb[t] = red[t] - ghist[t];
            hist[t] = 0;
            lcur[t] = 0;
        }
        __syncthreads();
        const int start = blockIdx.x * 2048;
        const int end = min(start + 2048, etot);
        for (int i = start + t; i < end; i += 256) {
            const int d = (i < e0) ? dsts[i] : (i - e0);
            atomicAdd(&hist[d >> 9], 1);
        }
        __syncthreads();
        if (t < 128) {
            const int c = hist[t];
            gbase[t] = c ? (sb[t] + atomicAdd(&cur[t], c)) : 0;
        }
        __syncthreads();
        for (int i = start + t; i < end; i += 256) {
            int s, d;
            if (i < e0) { s = srcs[i]; d = dsts[i]; } else { s = d = i - e0; }
            const int b = d >> 9;
            const int p = atomicAdd(&lcur[b], 1);
            pairs[gbase[b] + p] = s | ((d & 511) << 17);
        }
    } else {
        const int l = t & 63;
        const int w = t >> 6;                 // wave = output slab
        const int r0 = ((int)blockIdx.x - nblka) * 16;
        const int arow = min(r0 + (l & 15), n - 1);
        const int kb = (l >> 4) * 8;
        bf16x8 ah[4], al[4];
#pragma unroll
        for (int ks = 0; ks < 4; ++ks) {
            const float* ap = x + (size_t)arow * 128 + ks * 32 + kb;
            const float4 v0 = *reinterpret_cast<const float4*>(ap);
            const float4 v1 = *reinterpret_cast<const float4*>(ap + 4);
            const float fv[8] = {v0.x, v0.y, v0.z, v0.w, v1.x, v1.y, v1.z, v1.w};
#pragma unroll
            for (int j = 0; j < 8; ++j) {
                const ush h = f2bf(fv[j]);
                ah[ks][j] = (short)h;
                al[ks][j] = (short)f2bf(fv[j] - bf2f(h));
            }
        }
        const bool isW1 = w < 2;
        const int sl = w & 1;
        const ush* __restrict__ wh = isW1 ? wh1 : wh2;
        const ush* __restrict__ wl = isW1 ? wl1 : wl2;
        const int drow = (l >> 4) * 4;
        const int dcol = l & 15;
#pragma unroll
        for (int c16 = 0; c16 < 4; ++c16) {
            bf16x8 bh[4], bl[4];
#pragma unroll
            for (int ks = 0; ks < 4; ++ks) {
                const int fid = ks * 8 + sl * 4 + c16;
                bh[ks] = *reinterpret_cast<const bf16x8*>(wh + (size_t)(fid * 64 + l) * 8);
                bl[ks] = *reinterpret_cast<const bf16x8*>(wl + (size_t)(fid * 64 + l) * 8);
            }
            f32x4 acc = {0.f, 0.f, 0.f, 0.f};
#pragma unroll
            for (int ks = 0; ks < 4; ++ks) {
                acc = __builtin_amdgcn_mfma_f32_16x16x32_bf16(ah[ks], bh[ks], acc, 0, 0, 0);
                acc = __builtin_amdgcn_mfma_f32_16x16x32_bf16(al[ks], bh[ks], acc, 0, 0, 0);
                acc = __builtin_amdgcn_mfma_f32_16x16x32_bf16(ah[ks], bl[ks], acc, 0, 0, 0);
            }
            const int cg = sl * 64 + c16 * 16 + dcol;
#pragma unroll
            for (int q = 0; q < 4; ++q) {
                const int gr = r0 + drow + q;
                if (gr < n) {
                    if (isW1) ybf[(size_t)gr * 128 + cg] = f2bf(acc[q]);
                    else      yf[(size_t)gr * 128 + cg] = acc[q];
                }
            }
        }
    }
}

// ===== bucket_fill2: 512 dsts/bucket; row_ptr + csr fill + degree hist ======
__global__ __launch_bounds__(256) void bucket_fill2_k(
    const int* __restrict__ pairs, const int* __restrict__ ghist,
    int* __restrict__ row_ptr, int* __restrict__ csr_src,
    int* __restrict__ dbin, int n, int etot) {
    __shared__ int sb[128];
    __shared__ int red[256];
    __shared__ int cnt[512], cur[512], hcnt[128];
    const int b = blockIdx.x, t = threadIdx.x;
    // 128-wide exclusive scan of ghist -> bucket bounds
    if (t < 128) red[t] = ghist[t];
    __syncthreads();
#pragma unroll
    for (int s = 1; s < 128; s <<= 1) {
        const int add = (t < 128 && t >= s) ? red[t - s] : 0;
        __syncthreads();
        if (t < 128) red[t] += add;
        __syncthreads();
    }
    if (t < 128) sb[t] = red[t] - ghist[t];
    cnt[t] = 0; cnt[t + 256] = 0;
    if (t < 128) hcnt[t] = 0;
    __syncthreads();
    const int lo = sb[b];
    const int hi = (b + 1 < 128) ? sb[b + 1] : etot;
    for (int e = lo + t; e < hi; e += 256)
        atomicAdd(&cnt[(pairs[e] >> 17) & 511], 1);
    __syncthreads();
    // 512-wide exclusive scan, 2 elems/thread
    const int a0 = cnt[2 * t], a1 = cnt[2 * t + 1];
    red[t] = a0 + a1;
    __syncthreads();
#pragma unroll
    for (int s = 1; s < 256; s <<= 1) {
        const int add = (t >= s) ? red[t - s] : 0;
        __syncthreads();
        red[t] += add;
        __syncthreads();
    }
    const int base = red[t] - a0 - a1;
    cur[2 * t] = base;
    cur[2 * t + 1] = base + a0;
    {
        const int d0 = b * 512 + 2 * t;
        const int d1 = d0 + 1;
        if (d0 < n) {
            row_ptr[d0] = lo + base;
            atomicAdd(&hcnt[127 - min(a0, 127)], 1);
        }
        if (d1 < n) {
            row_ptr[d1] = lo + base + a0;
            atomicAdd(&hcnt[127 - min(a1, 127)], 1);
        }
    }
    if (b == 0 && t == 0) row_ptr[n] = etot;
    __syncthreads();
    if (t < 128 && hcnt[t]) atomicAdd(&dbin[t], hcnt[t]);
    for (int e = lo + t; e < hi; e += 256) {
        const int p = pairs[e];
        const int pos = atomicAdd(&cur[(p >> 17) & 511], 1);
        csr_src[lo + pos] = p & SRC_MASK;
    }
}

// ---- global degree-ordered permutation ----
__global__ __launch_bounds__(128) void deg_scan_k(const int* __restrict__ dbin,
                                                  int* __restrict__ dcur) {
    __shared__ int red[128];
    const int t = threadIdx.x;
    const int x = dbin[t];
    red[t] = x;
    __syncthreads();
#pragma unroll
    for (int s = 1; s < 128; s <<= 1) {
        const int add = (t >= s) ? red[t - s] : 0;
        __syncthreads();
        red[t] += add;
        __syncthreads();
    }
    dcur[t] = red[t] - x;
}

__global__ __launch_bounds__(256) void deg_scatter_k(const int* __restrict__ row_ptr,
                                                     int* __restrict__ dcur,
                                                     int* __restrict__ order, int n) {
    __shared__ int h[128], gbase[128], lcur[128];
    const int t = threadIdx.x;
    if (t < 128) { h[t] = 0; lcur[t] = 0; }
    __syncthreads();
    const int d = blockIdx.x * 256 + t;
    int bin = -1;
    if (d < n) {
        const int deg = row_ptr[d + 1] - row_ptr[d];
        bin = 127 - min(deg, 127);
        atomicAdd(&h[bin], 1);
    }
    __syncthreads();
    if (t < 128) gbase[t] = h[t] ? atomicAdd(&dcur[t], h[t]) : 0;
    __syncthreads();
    if (d < n) {
        const int p = atomicAdd(&lcur[bin], 1);
        order[gbase[bin] + p] = d;
    }
}

// ---------- layer-2 MFMA GEMM: 32 rows/block, wave = (slab, rowhalf) ----------
__global__ __launch_bounds__(256) void gemm2_k(
    const ush* __restrict__ ahi, const ush* __restrict__ alo,
    const ush* __restrict__ whl, const ush* __restrict__ wll,
    const ush* __restrict__ whr, const ush* __restrict__ wlr,
    ush* __restrict__ ybf, float* __restrict__ yf, int n) {
    const int l = threadIdx.x & 63;
    const int w = threadIdx.x >> 6;
    const int slab = w >> 1, rh = w & 1;
    const int r0 = blockIdx.x * 32 + rh * 16;
    const int arow = min(r0 + (l & 15), n - 1);
    const int kb = (l >> 4) * 8;
    bf16x8 ah[4], al[4];
#pragma unroll
    for (int ks = 0; ks < 4; ++ks) {
        ah[ks] = *reinterpret_cast<const bf16x8*>(ahi + (size_t)arow * 128 + ks * 32 + kb);
        al[ks] = *reinterpret_cast<const bf16x8*>(alo + (size_t)arow * 128 + ks * 32 + kb);
    }
    const ush* __restrict__ wh = slab ? whr : whl;
    const ush* __restrict__ wl = slab ? wlr : wll;
    const int drow = (l >> 4) * 4;
    const int dcol = l & 15;
#pragma unroll
    for (int c16 = 0; c16 < 4; ++c16) {
        bf16x8 bh[4], bl[4];
#pragma unroll
        for (int ks = 0; ks < 4; ++ks) {
            const int fid = ks * 4 + c16;
            bh[ks] = *reinterpret_cast<const bf16x8*>(wh + (size_t)(fid * 64 + l) * 8);
            bl[ks] = *reinterpret_cast<const bf16x8*>(wl + (size_t)(fid * 64 + l) * 8);
        }
        f32x4 acc = {0.f, 0.f, 0.f, 0.f};
#pragma unroll
        for (int ks = 0; ks < 4; ++ks) {
            acc = __builtin_amdgcn_mfma_f32_16x16x32_bf16(ah[ks], bh[ks], acc, 0, 0, 0);
            acc = __builtin_amdgcn_mfma_f32_16x16x32_bf16(al[ks], bh[ks], acc, 0, 0, 0);
            acc = __builtin_amdgcn_mfma_f32_16x16x32_bf16(ah[ks], bl[ks], acc, 0, 0, 0);
        }
        const int cg = c16 * 16 + dcol;
#pragma unroll
        for (int q = 0; q < 4; ++q) {
            const int gr = r0 + drow + q;
            if (gr < n) {
                if (slab == 0) ybf[(size_t)gr * 64 + cg] = f2bf(acc[q]);
                else           yf[(size_t)gr * 64 + cg] = acc[q];
            }
        }
    }
}

// ---------- fused per-dst softmax aggregation, H=2 (128 cols, xl bf16) ----------
__global__ __launch_bounds__(256) void gat_dst2_k(
    const ush* __restrict__ xl, const float* __restrict__ xr,
    const int* __restrict__ row_ptr, const int* __restrict__ csr_src,
    const int* __restrict__ order, const float* __restrict__ att,
    const float* __restrict__ bias, ush* __restrict__ h1hi,
    ush* __restrict__ h1lo, int n) {
    const int lane = threadIdx.x & 63;
    const int g = lane >> 4, il = lane & 15;
    const int w = (blockIdx.x * blockDim.x + threadIdx.x) >> 6;
    if (w >= n) return;
    const int d = order[w];

    float xv[8], av[8];
    {
        const float4* xp = reinterpret_cast<const float4*>(xr + (size_t)d * 128 + il * 8);
        const float4* ap = reinterpret_cast<const float4*>(att + il * 8);
        const float4 x0 = xp[0], x1 = xp[1], a0 = ap[0], a1 = ap[1];
        xv[0]=x0.x; xv[1]=x0.y; xv[2]=x0.z; xv[3]=x0.w;
        xv[4]=x1.x; xv[5]=x1.y; xv[6]=x1.z; xv[7]=x1.w;
        av[0]=a0.x; av[1]=a0.y; av[2]=a0.z; av[3]=a0.w;
        av[4]=a1.x; av[5]=a1.y; av[6]=a1.z; av[7]=a1.w;
    }
    const int rp0 = row_ptr[d], rp1 = row_ptr[d + 1];

    float s = 0.f;
    float acc[8] = {0.f, 0.f, 0.f, 0.f, 0.f, 0.f, 0.f, 0.f};
    int i = rp0 + g;
    for (; i + 4 < rp1; i += 8) {
        const int s0 = csr_src[i];
        const int s1 = csr_src[i + 4];
        const ushx8 u0 = *reinterpret_cast<const ushx8*>(xl + (((size_t)(unsigned)s0) << 7) + il * 8);
        const ushx8 u1 = *reinterpret_cast<const ushx8*>(xl + (((size_t)(unsigned)s1) << 7) + il * 8);
        float f0[8], f1[8], p0 = 0.f, p1 = 0.f;
#pragma unroll
        for (int j = 0; j < 8; ++j) {
            f0[j] = bf2f((ush)u0[j]);
            const float v = f0[j] + xv[j];
            p0 = fmaf(av[j], fmaxf(v, 0.2f * v), p0);
        }
#pragma unroll
        for (int j = 0; j < 8; ++j) {
            f1[j] = bf2f((ush)u1[j]);
            const float v = f1[j] + xv[j];
            p1 = fmaf(av[j], fmaxf(v, 0.2f * v), p1);
        }
        p0 += __shfl_xor(p0, 4, 64); p0 += __shfl_xor(p0, 2, 64); p0 += __shfl_xor(p0, 1, 64);
        p1 += __shfl_xor(p1, 4, 64); p1 += __shfl_xor(p1, 2, 64); p1 += __shfl_xor(p1, 1, 64);
        const float w0 = __expf(p0), w1 = __expf(p1);
        s += w0 + w1;
#pragma unroll
        for (int j = 0; j < 8; ++j) acc[j] = fmaf(w0, f0[j], fmaf(w1, f1[j], acc[j]));
    }
    if (i < rp1) {
        const int s0 = csr_src[i];
        const ushx8 u0 = *reinterpret_cast<const ushx8*>(xl + (((size_t)(unsigned)s0) << 7) + il * 8);
        float f0[8], p0 = 0.f;
#pragma unroll
        for (int j = 0; j < 8; ++j) {
            f0[j] = bf2f((ush)u0[j]);
            const float v = f0[j] + xv[j];
            p0 = fmaf(av[j], fmaxf(v, 0.2f * v), p0);
        }
        p0 += __shfl_xor(p0, 4, 64); p0 += __shfl_xor(p0, 2, 64); p0 += __shfl_xor(p0, 1, 64);
        const float w0 = __expf(p0);
        s += w0;
#pragma unroll
        for (int j = 0; j < 8; ++j) acc[j] = fmaf(w0, f0[j], acc[j]);
    }
#pragma unroll
    for (int off = 16; off <= 32; off <<= 1) {
        s += __shfl_xor(s, off, 64);
#pragma unroll
        for (int j = 0; j < 8; ++j) acc[j] += __shfl_xor(acc[j], off, 64);
    }
    if (g == 0) {
        const float inv = 1.f / (s + 1e-16f);
        float bv[8];
        {
            const float4* bp = reinterpret_cast<const float4*>(bias + il * 8);
            const float4 b0 = bp[0], b1 = bp[1];
            bv[0]=b0.x; bv[1]=b0.y; bv[2]=b0.z; bv[3]=b0.w;
            bv[4]=b1.x; bv[5]=b1.y; bv[6]=b1.z; bv[7]=b1.w;
        }
        ushx8 hh, ll;
#pragma unroll
        for (int j = 0; j < 8; ++j) {
            const float o = fmaxf(fmaf(acc[j], inv, bv[j]), 0.f);
            const ush h = f2bf(o);
            hh[j] = h;
            ll[j] = f2bf(o - bf2f(h));
        }
        *reinterpret_cast<ushx8*>(h1hi + (size_t)d * 128 + il * 8) = hh;
        *reinterpret_cast<ushx8*>(h1lo + (size_t)d * 128 + il * 8) = ll;
    }
}

// ---------- fused per-dst softmax aggregation, H=1 (64 cols, xl bf16) ----------
__global__ __launch_bounds__(256) void gat_dst1_k(
    const ush* __restrict__ xl, const float* __restrict__ xr,
    const int* __restrict__ row_ptr, const int* __restrict__ csr_src,
    const int* __restrict__ order, const float* __restrict__ att,
    const float* __restrict__ bias, float* __restrict__ out, int n) {
    const int lane = threadIdx.x & 63;
    const int g = lane >> 3, il = lane & 7;
    const int w = (blockIdx.x * blockDim.x + threadIdx.x) >> 6;
    if (w >= n) return;
    const int d = order[w];

    float xv[8], av[8];
    {
        const float4* xp = reinterpret_cast<const float4*>(xr + (size_t)d * 64 + il * 8);
        const float4* ap = reinterpret_cast<const float4*>(att + il * 8);
        const float4 x0 = xp[0], x1 = xp[1], a0 = ap[0], a1 = ap[1];
        xv[0]=x0.x; xv[1]=x0.y; xv[2]=x0.z; xv[3]=x0.w;
        xv[4]=x1.x; xv[5]=x1.y; xv[6]=x1.z; xv[7]=x1.w;
        av[0]=a0.x; av[1]=a0.y; av[2]=a0.z; av[3]=a0.w;
        av[4]=a1.x; av[5]=a1.y; av[6]=a1.z; av[7]=a1.w;
    }
    const int rp0 = row_ptr[d], rp1 = row_ptr[d + 1];

    float s = 0.f;
    float acc[8] = {0.f, 0.f, 0.f, 0.f, 0.f, 0.f, 0.f, 0.f};
    int i = rp0 + g;
    for (; i + 8 < rp1; i += 16) {
        const int s0 = csr_src[i];
        const int s1 = csr_src[i + 8];
        const ushx8 u0 = *reinterpret_cast<const ushx8*>(xl + (((size_t)(unsigned)s0) << 6) + il * 8);
        const ushx8 u1 = *reinterpret_cast<const ushx8*>(xl + (((size_t)(unsigned)s1) << 6) + il * 8);
        float f0[8], f1[8], p0 = 0.f, p1 = 0.f;
#pragma unroll
        for (int j = 0; j < 8; ++j) {
            f0[j] = bf2f((ush)u0[j]);
            const float v = f0[j] + xv[j];
            p0 = fmaf(av[j], fmaxf(v, 0.2f * v), p0);
        }
#pragma unroll
        for (int j = 0; j < 8; ++j) {
            f1[j] = bf2f((ush)u1[j]);
            const float v = f1[j] + xv[j];
            p1 = fmaf(av[j], fmaxf(v, 0.2f * v), p1);
        }
        p0 += __shfl_xor(p0, 4, 64); p0 += __shfl_xor(p0, 2, 64); p0 += __shfl_xor(p0, 1, 64);
        p1 += __shfl_xor(p1, 4, 64); p1 += __shfl_xor(p1, 2, 64); p1 += __shfl_xor(p1, 1, 64);
        const float w0 = __expf(p0), w1 = __expf(p1);
        s += w0 + w1;
#pragma unroll
        for (int j = 0; j < 8; ++j) acc[j] = fmaf(w0, f0[j], fmaf(w1, f1[j], acc[j]));
    }
    if (i < rp1) {
        const int s0 = csr_src[i];
        const ushx8 u0 = *reinterpret_cast<const ushx8*>(xl + (((size_t)(unsigned)s0) << 6) + il * 8);
        float f0[8], p0 = 0.f;
#pragma unroll
        for (int j = 0; j < 8; ++j) {
            f0[j] = bf2f((ush)u0[j]);
            const float v = f0[j] + xv[j];
            p0 = fmaf(av[j], fmaxf(v, 0.2f * v), p0);
        }
        p0 += __shfl_xor(p0, 4, 64); p0 += __shfl_xor(p0, 2, 64); p0 += __shfl_xor(p0, 1, 64);
        const float w0 = __expf(p0);
        s += w0;
#pragma unroll
        for (int j = 0; j < 8; ++j) acc[j] = fmaf(w0, f0[j], acc[j]);
    }
#pragma unroll
    for (int off = 8; off <= 32; off <<= 1) {
        s += __shfl_xor(s, off, 64);
#pragma unroll
        for (int j = 0; j < 8; ++j) acc[j] += __shfl_xor(acc[j], off, 64);
    }
    if (g == 0) {
        const float inv = 1.f / (s + 1e-16f);
        float bv[8];
        {
            const float4* bp = reinterpret_cast<const float4*>(bias + il * 8);
            const float4 b0 = bp[0], b1 = bp[1];
            bv[0]=b0.x; bv[1]=b0.y; bv[2]=b0.z; bv[3]=b0.w;
            bv[4]=b1.x; bv[5]=b1.y; bv[6]=b1.z; bv[7]=b1.w;
        }
        float4 o0, o1;
        o0.x = fmaxf(fmaf(acc[0], inv, bv[0]), 0.f);
        o0.y = fmaxf(fmaf(acc[1], inv, bv[1]), 0.f);
        o0.z = fmaxf(fmaf(acc[2], inv, bv[2]), 0.f);
        o0.w = fmaxf(fmaf(acc[3], inv, bv[3]), 0.f);
        o1.x = fmaxf(fmaf(acc[4], inv, bv[4]), 0.f);
        o1.y = fmaxf(fmaf(acc[5], inv, bv[5]), 0.f);
        o1.z = fmaxf(fmaf(acc[6], inv, bv[6]), 0.f);
        o1.w = fmaxf(fmaf(acc[7], inv, bv[7]), 0.f);
        float4* op = reinterpret_cast<float4*>(out + (size_t)d * 64 + il * 8);
        op[0] = o0;
        op[1] = o1;
    }
}

extern "C" void kernel_launch(void* const* d_in, const int* in_sizes, int n_in,
                              void* d_out, int out_size, void* d_ws, size_t ws_size,
                              hipStream_t stream) {
    const float* x    = (const float*)d_in[0];
    const int*   ei   = (const int*)d_in[1];
    const float* Wl1  = (const float*)d_in[2];
    const float* Wr1  = (const float*)d_in[3];
    const float* att1 = (const float*)d_in[4];
    const float* b1   = (const float*)d_in[5];
    const float* Wl2  = (const float*)d_in[6];
    const float* Wr2  = (const float*)d_in[7];
    const float* att2 = (const float*)d_in[8];
    const float* b2   = (const float*)d_in[9];

    const int n    = in_sizes[0] / 128;   // 50000
    const int e0   = in_sizes[1] / 2;     // 800000
    const int etot = e0 + n;
    const int* srcs = ei;
    const int* dsts = ei + e0;

    float* ws = (float*)d_ws;
    ush*   h1hi = (ush*)ws;                        // n*128 ush
    ush*   h1lo = (ush*)(ws + (size_t)n * 64);     // n*128 ush
    ush*   xlbf = (ush*)(ws + (size_t)n * 128);    // n*128 ush
    float* xr   = ws + (size_t)n * 192;            // n*128 f32
    int* row_ptr = (int*)(ws + (size_t)n * 320);   // n+2
    int* ghist   = row_ptr + (n + 2);              // 128
    int* cur     = ghist + 128;                    // 128
    int* dbin    = cur + 128;                      // 128
    int* dcur    = dbin + 128;                     // 128
    int* order   = dcur + 128;                     // n
    int* csr_src = order + n;                      // etot
    int* pairs   = csr_src + etot;                 // etot (packed)
    ush* wph     = (ush*)(pairs + etot);           // 96*512 ush
    ush* wpl     = wph + 96 * 512;                 // 96*512 ush

    const int NB    = (n + 511) / 512;             // 98 <= 128
    const int NDB   = (n + 255) / 256;             // 196
    const int nblka = (etot + 2047) / 2048;        // 416
    const int g1    = (n + 15) / 16;               // 3125 (gemm1: 16 rows/block)
    const int g2    = (n + 31) / 32;               // 1563 (gemm2: 32 rows/block)

    // 1) zero ghist + cur + dbin
    hipMemsetAsync(ghist, 0, 384 * sizeof(int), stream);
    // 2) hist (256 blocks) + prep_w (24 blocks)
    fusedA_k<<<256 + 24, 256, 0, stream>>>(dsts, ghist, Wl1, Wr1, Wl2, Wr2,
                                           wph, wpl, e0, etot);
    // 3) semisort (nblka blocks) + layer-1 GEMM (g1 blocks)
    fusedB_k<<<nblka + g1, 256, 0, stream>>>(
        srcs, dsts, ghist, cur, pairs, x,
        wph, wpl, wph + 32 * 512, wpl + 32 * 512, xlbf, xr,
        e0, etot, nblka, n);
    // 4) row_ptr + csr_src + global degree hist (512 dsts/bucket)
    bucket_fill2_k<<<NB, 256, 0, stream>>>(pairs, ghist, row_ptr, csr_src,
                                           dbin, n, etot);
    // 5) global degree order
    deg_scan_k<<<1, 128, 0, stream>>>(dbin, dcur);
    deg_scatter_k<<<NDB, 256, 0, stream>>>(row_ptr, dcur, order, n);
    // 6) layer-1 attention
    gat_dst2_k<<<(n + 3) / 4, 256, 0, stream>>>(xlbf, xr, row_ptr, csr_src, order,
                                                att1, b1, h1hi, h1lo, n);
    // 7) layer-2 GEMM
    gemm2_k<<<g2, 256, 0, stream>>>(h1hi, h1lo, wph + 64 * 512, wpl + 64 * 512,
                                    wph + 80 * 512, wpl + 80 * 512, xlbf, xr, n);
    // 8) layer-2 attention
    gat_dst1_k<<<(n + 3) / 4, 256, 0, stream>>>(xlbf, xr, row_ptr, csr_src, order,
                                                att2, b2, (float*)d_out, n);
}

// Round 20
// 184.128 us; speedup vs baseline: 1.0307x; 1.0307x over previous
//
#include <hip/hip_runtime.h>
#include <math.h>

typedef unsigned short ush;
typedef short bf16x8 __attribute__((ext_vector_type(8)));
typedef float f32x4 __attribute__((ext_vector_type(4)));
typedef ush ushx8 __attribute__((ext_vector_type(8)));

// ---------- bf16 helpers ----------
__device__ __forceinline__ ush f2bf(float f) {
    unsigned u = __float_as_uint(f);
    u += 0x7FFFu + ((u >> 16) & 1u);
    return (ush)(u >> 16);
}
__device__ __forceinline__ float bf2f(ush u) {
    return __uint_as_float((unsigned)u << 16);
}

// ================= fused A: hist (blocks 0..255) + prep_w (blocks 256..279) ====
__global__ __launch_bounds__(256) void fusedA_k(
    const int* __restrict__ dsts, int* __restrict__ ghist,
    const float* __restrict__ Wl1, const float* __restrict__ Wr1,
    const float* __restrict__ Wl2, const float* __restrict__ Wr2,
    ush* __restrict__ wph, ush* __restrict__ wpl, int e0, int etot) {
    const int t = threadIdx.x;
    if (blockIdx.x < 256) {
        __shared__ int h[512];
        for (int i = t; i < 512; i += 256) h[i] = 0;
        __syncthreads();
        for (int i = blockIdx.x * 256 + t; i < etot; i += 256 * 256) {
            const int d = (i < e0) ? dsts[i] : (i - e0);
            atomicAdd(&h[d >> 7], 1);
        }
        __syncthreads();
        for (int i = t; i < 512; i += 256)
            if (h[i]) atomicAdd(&ghist[i], h[i]);
    } else {
        const int bid = (blockIdx.x - 256) * 4 + (t >> 6);
        const int l = t & 63;
        const float* W;
        int C, fid;
        if (bid < 32)      { W = Wl1; C = 128; fid = bid; }
        else if (bid < 64) { W = Wr1; C = 128; fid = bid - 32; }
        else if (bid < 80) { W = Wl2; C = 64;  fid = bid - 64; }
        else               { W = Wr2; C = 64;  fid = bid - 80; }
        const int nc16 = C / 16;
        const int ks = fid / nc16, c16 = fid % nc16;
#pragma unroll
        for (int j = 0; j < 8; ++j) {
            const int k = ks * 32 + (l >> 4) * 8 + j;
            const int c = c16 * 16 + (l & 15);
            const float v = W[(size_t)k * C + c];
            const ush h = f2bf(v);
            wph[(size_t)(bid * 64 + l) * 8 + j] = h;
            wpl[(size_t)(bid * 64 + l) * 8 + j] = f2bf(v - bf2f(h));
        }
    }
}

// ================= fused B: semisort (blocks < nblka) + gemm1 (rest) ==========
// gemm1: 16 rows/block, wave = output slab; ks-outer loop with 4 independent
// accumulator chains (c16) for MFMA ILP.
__global__ __launch_bounds__(256) void fusedB_k(
    const int* __restrict__ srcs, const int* __restrict__ dsts,
    const int* __restrict__ ghist, int* __restrict__ cur, int* __restrict__ pairs,
    const float* __restrict__ x,
    const ush* __restrict__ wh1, const ush* __restrict__ wl1,
    const ush* __restrict__ wh2, const ush* __restrict__ wl2,
    ush* __restrict__ ybf, float* __restrict__ yf,
    int e0, int etot, int nblka, int n) {
    const int t = threadIdx.x;
    if ((int)blockIdx.x < nblka) {
        __shared__ int sb[512];
        __shared__ int red[256];
        __shared__ int hist[512], gbase[512], lcur[512];
        const int a0 = ghist[2 * t], a1 = ghist[2 * t + 1];
        red[t] = a0 + a1;
        __syncthreads();
#pragma unroll
        for (int s = 1; s < 256; s <<= 1) {
            const int add = (t >= s) ? red[t - s] : 0;
            __syncthreads();
            red[t] += add;
            __syncthreads();
        }
        const int base = red[t] - a0 - a1;
        sb[2 * t] = base;
        sb[2 * t + 1] = base + a0;
        for (int i = t; i < 512; i += 256) { hist[i] = 0; lcur[i] = 0; }
        __syncthreads();
        const int start = blockIdx.x * 2048;
        const int end = min(start + 2048, etot);
        for (int i = start + t; i < end; i += 256) {
            const int d = (i < e0) ? dsts[i] : (i - e0);
            atomicAdd(&hist[d >> 7], 1);
        }
        __syncthreads();
        for (int i = t; i < 512; i += 256) {
            const int c = hist[i];
            gbase[i] = c ? (sb[i] + atomicAdd(&cur[i], c)) : 0;
        }
        __syncthreads();
        for (int i = start + t; i < end; i += 256) {
            int s, d;
            if (i < e0) { s = srcs[i]; d = dsts[i]; } else { s = d = i - e0; }
            const int b = d >> 7;
            const int p = atomicAdd(&lcur[b], 1);
            pairs[gbase[b] + p] = s | ((d & 127) << 24);
        }
    } else {
        const int l = t & 63;
        const int w = t >> 6;                 // wave = output slab
        const int r0 = ((int)blockIdx.x - nblka) * 16;
        const int arow = min(r0 + (l & 15), n - 1);
        const int kb = (l >> 4) * 8;
        bf16x8 ah[4], al[4];
#pragma unroll
        for (int ks = 0; ks < 4; ++ks) {
            const float* ap = x + (size_t)arow * 128 + ks * 32 + kb;
            const float4 v0 = *reinterpret_cast<const float4*>(ap);
            const float4 v1 = *reinterpret_cast<const float4*>(ap + 4);
            const float fv[8] = {v0.x, v0.y, v0.z, v0.w, v1.x, v1.y, v1.z, v1.w};
#pragma unroll
            for (int j = 0; j < 8; ++j) {
                const ush h = f2bf(fv[j]);
                ah[ks][j] = (short)h;
                al[ks][j] = (short)f2bf(fv[j] - bf2f(h));
            }
        }
        const bool isW1 = w < 2;
        const int sl = w & 1;
        const ush* __restrict__ wh = isW1 ? wh1 : wh2;
        const ush* __restrict__ wl = isW1 ? wl1 : wl2;
        const int drow = (l >> 4) * 4;
        const int dcol = l & 15;
        f32x4 acc[4];
#pragma unroll
        for (int c16 = 0; c16 < 4; ++c16) acc[c16] = {0.f, 0.f, 0.f, 0.f};
#pragma unroll
        for (int ks = 0; ks < 4; ++ks) {
            bf16x8 bh[4], bl[4];
#pragma unroll
            for (int c16 = 0; c16 < 4; ++c16) {
                const int fid = ks * 8 + sl * 4 + c16;
                bh[c16] = *reinterpret_cast<const bf16x8*>(wh + (size_t)(fid * 64 + l) * 8);
                bl[c16] = *reinterpret_cast<const bf16x8*>(wl + (size_t)(fid * 64 + l) * 8);
            }
            // 12 MFMAs spread over 4 independent chains
#pragma unroll
            for (int c16 = 0; c16 < 4; ++c16)
                acc[c16] = __builtin_amdgcn_mfma_f32_16x16x32_bf16(ah[ks], bh[c16], acc[c16], 0, 0, 0);
#pragma unroll
            for (int c16 = 0; c16 < 4; ++c16)
                acc[c16] = __builtin_amdgcn_mfma_f32_16x16x32_bf16(al[ks], bh[c16], acc[c16], 0, 0, 0);
#pragma unroll
            for (int c16 = 0; c16 < 4; ++c16)
                acc[c16] = __builtin_amdgcn_mfma_f32_16x16x32_bf16(ah[ks], bl[c16], acc[c16], 0, 0, 0);
        }
#pragma unroll
        for (int c16 = 0; c16 < 4; ++c16) {
            const int cg = sl * 64 + c16 * 16 + dcol;
#pragma unroll
            for (int q = 0; q < 4; ++q) {
                const int gr = r0 + drow + q;
                if (gr < n) {
                    if (isW1) ybf[(size_t)gr * 128 + cg] = f2bf(acc[c16][q]);
                    else      yf[(size_t)gr * 128 + cg] = acc[c16][q];
                }
            }
        }
    }
}

// ===== bucket_fill2: row_ptr + csr fill + global degree histogram (R16) ======
__global__ __launch_bounds__(256) void bucket_fill2_k(
    const int* __restrict__ pairs, const int* __restrict__ ghist,
    int* __restrict__ row_ptr, int* __restrict__ csr_src,
    int* __restrict__ dbin, int n, int etot) {
    __shared__ int sb[512];
    __shared__ int red[256];
    __shared__ int cnt[128], cur[128], hcnt[128];
    const int b = blockIdx.x, t = threadIdx.x;
    const int a0 = ghist[2 * t], a1 = ghist[2 * t + 1];
    red[t] = a0 + a1;
    __syncthreads();
#pragma unroll
    for (int s = 1; s < 256; s <<= 1) {
        const int add = (t >= s) ? red[t - s] : 0;
        __syncthreads();
        red[t] += add;
        __syncthreads();
    }
    const int base = red[t] - a0 - a1;
    sb[2 * t] = base;
    sb[2 * t + 1] = base + a0;
    if (t < 128) { cnt[t] = 0; hcnt[t] = 0; }
    __syncthreads();
    const int lo = sb[b];
    const int hi = (b + 1 < 512) ? sb[b + 1] : etot;
    for (int e = lo + t; e < hi; e += 256)
        atomicAdd(&cnt[(pairs[e] >> 24) & 127], 1);
    __syncthreads();
    const int x = (t < 128) ? cnt[t] : 0;
#pragma unroll
    for (int s = 1; s < 128; s <<= 1) {
        const int add = (t < 128 && t >= s) ? cnt[t - s] : 0;
        __syncthreads();
        if (t < 128) cnt[t] += add;
        __syncthreads();
    }
    if (t < 128) {
        const int excl = cnt[t] - x;
        cur[t] = excl;
        const int d = b * 128 + t;
        if (d < n) {
            row_ptr[d] = lo + excl;
            atomicAdd(&hcnt[127 - min(x, 127)], 1);
        }
    }
    if (b == 0 && t == 0) row_ptr[n] = etot;
    __syncthreads();
    if (t < 128 && hcnt[t]) atomicAdd(&dbin[t], hcnt[t]);
    for (int e = lo + t; e < hi; e += 256) {
        const int p = pairs[e];
        const int pos = atomicAdd(&cur[(p >> 24) & 127], 1);
        csr_src[lo + pos] = p & 0xFFFFFF;
    }
}

// ---- global degree order: local scan of dbin + zeroed global cursor ----
__global__ __launch_bounds__(256) void deg_scatter2_k(
    const int* __restrict__ row_ptr, const int* __restrict__ dbin,
    int* __restrict__ dcur, int* __restrict__ order, int n) {
    __shared__ int excl[128], red[128];
    __shared__ int h[128], gbase[128], lcur[128];
    const int t = threadIdx.x;
    if (t < 128) red[t] = dbin[t];
    __syncthreads();
#pragma unroll
    for (int s = 1; s < 128; s <<= 1) {
        const int add = (t < 128 && t >= s) ? red[t - s] : 0;
        __syncthreads();
        if (t < 128) red[t] += add;
        __syncthreads();
    }
    if (t < 128) {
        excl[t] = red[t] - dbin[t];
        h[t] = 0;
        lcur[t] = 0;
    }
    __syncthreads();
    const int d = blockIdx.x * 256 + t;
    int bin = -1;
    if (d < n) {
        const int deg = row_ptr[d + 1] - row_ptr[d];
        bin = 127 - min(deg, 127);
        atomicAdd(&h[bin], 1);
    }
    __syncthreads();
    if (t < 128) gbase[t] = h[t] ? (excl[t] + atomicAdd(&dcur[t], h[t])) : 0;
    __syncthreads();
    if (d < n) {
        const int p = atomicAdd(&lcur[bin], 1);
        order[gbase[bin] + p] = d;
    }
}

// ---------- layer-2 MFMA GEMM: 32 rows/block, wave = (slab,rowhalf); ----------
// ks-outer with 4 independent accumulator chains.
__global__ __launch_bounds__(256) void gemm2_k(
    const ush* __restrict__ ahi, const ush* __restrict__ alo,
    const ush* __restrict__ whl, const ush* __restrict__ wll,
    const ush* __restrict__ whr, const ush* __restrict__ wlr,
    ush* __restrict__ ybf, float* __restrict__ yf, int n) {
    const int l = threadIdx.x & 63;
    const int w = threadIdx.x >> 6;
    const int slab = w >> 1, rh = w & 1;
    const int r0 = blockIdx.x * 32 + rh * 16;
    const int arow = min(r0 + (l & 15), n - 1);
    const int kb = (l >> 4) * 8;
    bf16x8 ah[4], al[4];
#pragma unroll
    for (int ks = 0; ks < 4; ++ks) {
        ah[ks] = *reinterpret_cast<const bf16x8*>(ahi + (size_t)arow * 128 + ks * 32 + kb);
        al[ks] = *reinterpret_cast<const bf16x8*>(alo + (size_t)arow * 128 + ks * 32 + kb);
    }
    const ush* __restrict__ wh = slab ? whr : whl;
    const ush* __restrict__ wl = slab ? wlr : wll;
    const int drow = (l >> 4) * 4;
    const int dcol = l & 15;
    f32x4 acc[4];
#pragma unroll
    for (int c16 = 0; c16 < 4; ++c16) acc[c16] = {0.f, 0.f, 0.f, 0.f};
#pragma unroll
    for (int ks = 0; ks < 4; ++ks) {
        bf16x8 bh[4], bl[4];
#pragma unroll
        for (int c16 = 0; c16 < 4; ++c16) {
            const int fid = ks * 4 + c16;
            bh[c16] = *reinterpret_cast<const bf16x8*>(wh + (size_t)(fid * 64 + l) * 8);
            bl[c16] = *reinterpret_cast<const bf16x8*>(wl + (size_t)(fid * 64 + l) * 8);
        }
#pragma unroll
        for (int c16 = 0; c16 < 4; ++c16)
            acc[c16] = __builtin_amdgcn_mfma_f32_16x16x32_bf16(ah[ks], bh[c16], acc[c16], 0, 0, 0);
#pragma unroll
        for (int c16 = 0; c16 < 4; ++c16)
            acc[c16] = __builtin_amdgcn_mfma_f32_16x16x32_bf16(al[ks], bh[c16], acc[c16], 0, 0, 0);
#pragma unroll
        for (int c16 = 0; c16 < 4; ++c16)
            acc[c16] = __builtin_amdgcn_mfma_f32_16x16x32_bf16(ah[ks], bl[c16], acc[c16], 0, 0, 0);
    }
#pragma unroll
    for (int c16 = 0; c16 < 4; ++c16) {
        const int cg = c16 * 16 + dcol;
#pragma unroll
        for (int q = 0; q < 4; ++q) {
            const int gr = r0 + drow + q;
            if (gr < n) {
                if (slab == 0) ybf[(size_t)gr * 64 + cg] = f2bf(acc[c16][q]);
                else           yf[(size_t)gr * 64 + cg] = acc[c16][q];
            }
        }
    }
}

// ---------- fused per-dst softmax aggregation, H=2 (128 cols, xl bf16) ----------
__global__ __launch_bounds__(256) void gat_dst2_k(
    const ush* __restrict__ xl, const float* __restrict__ xr,
    const int* __restrict__ row_ptr, const int* __restrict__ csr_src,
    const int* __restrict__ order, const float* __restrict__ att,
    const float* __restrict__ bias, ush* __restrict__ h1hi,
    ush* __restrict__ h1lo, int n) {
    const int lane = threadIdx.x & 63;
    const int g = lane >> 4, il = lane & 15;
    const int w = (blockIdx.x * blockDim.x + threadIdx.x) >> 6;
    if (w >= n) return;
    const int d = order[w];

    float xv[8], av[8];
    {
        const float4* xp = reinterpret_cast<const float4*>(xr + (size_t)d * 128 + il * 8);
        const float4* ap = reinterpret_cast<const float4*>(att + il * 8);
        const float4 x0 = xp[0], x1 = xp[1], a0 = ap[0], a1 = ap[1];
        xv[0]=x0.x; xv[1]=x0.y; xv[2]=x0.z; xv[3]=x0.w;
        xv[4]=x1.x; xv[5]=x1.y; xv[6]=x1.z; xv[7]=x1.w;
        av[0]=a0.x; av[1]=a0.y; av[2]=a0.z; av[3]=a0.w;
        av[4]=a1.x; av[5]=a1.y; av[6]=a1.z; av[7]=a1.w;
    }
    const int rp0 = row_ptr[d], rp1 = row_ptr[d + 1];

    float s = 0.f;
    float acc[8] = {0.f, 0.f, 0.f, 0.f, 0.f, 0.f, 0.f, 0.f};
    int i = rp0 + g;
    for (; i + 4 < rp1; i += 8) {
        const int s0 = csr_src[i];
        const int s1 = csr_src[i + 4];
        const ushx8 u0 = *reinterpret_cast<const ushx8*>(xl + (((size_t)(unsigned)s0) << 7) + il * 8);
        const ushx8 u1 = *reinterpret_cast<const ushx8*>(xl + (((size_t)(unsigned)s1) << 7) + il * 8);
        float f0[8], f1[8], p0 = 0.f, p1 = 0.f;
#pragma unroll
        for (int j = 0; j < 8; ++j) {
            f0[j] = bf2f((ush)u0[j]);
            const float v = f0[j] + xv[j];
            p0 = fmaf(av[j], fmaxf(v, 0.2f * v), p0);
        }
#pragma unroll
        for (int j = 0; j < 8; ++j) {
            f1[j] = bf2f((ush)u1[j]);
            const float v = f1[j] + xv[j];
            p1 = fmaf(av[j], fmaxf(v, 0.2f * v), p1);
        }
        p0 += __shfl_xor(p0, 4, 64); p0 += __shfl_xor(p0, 2, 64); p0 += __shfl_xor(p0, 1, 64);
        p1 += __shfl_xor(p1, 4, 64); p1 += __shfl_xor(p1, 2, 64); p1 += __shfl_xor(p1, 1, 64);
        const float w0 = __expf(p0), w1 = __expf(p1);
        s += w0 + w1;
#pragma unroll
        for (int j = 0; j < 8; ++j) acc[j] = fmaf(w0, f0[j], fmaf(w1, f1[j], acc[j]));
    }
    if (i < rp1) {
        const int s0 = csr_src[i];
        const ushx8 u0 = *reinterpret_cast<const ushx8*>(xl + (((size_t)(unsigned)s0) << 7) + il * 8);
        float f0[8], p0 = 0.f;
#pragma unroll
        for (int j = 0; j < 8; ++j) {
            f0[j] = bf2f((ush)u0[j]);
            const float v = f0[j] + xv[j];
            p0 = fmaf(av[j], fmaxf(v, 0.2f * v), p0);
        }
        p0 += __shfl_xor(p0, 4, 64); p0 += __shfl_xor(p0, 2, 64); p0 += __shfl_xor(p0, 1, 64);
        const float w0 = __expf(p0);
        s += w0;
#pragma unroll
        for (int j = 0; j < 8; ++j) acc[j] = fmaf(w0, f0[j], acc[j]);
    }
#pragma unroll
    for (int off = 16; off <= 32; off <<= 1) {
        s += __shfl_xor(s, off, 64);
#pragma unroll
        for (int j = 0; j < 8; ++j) acc[j] += __shfl_xor(acc[j], off, 64);
    }
    if (g == 0) {
        const float inv = 1.f / (s + 1e-16f);
        float bv[8];
        {
            const float4* bp = reinterpret_cast<const float4*>(bias + il * 8);
            const float4 b0 = bp[0], b1 = bp[1];
            bv[0]=b0.x; bv[1]=b0.y; bv[2]=b0.z; bv[3]=b0.w;
            bv[4]=b1.x; bv[5]=b1.y; bv[6]=b1.z; bv[7]=b1.w;
        }
        ushx8 hh, ll;
#pragma unroll
        for (int j = 0; j < 8; ++j) {
            const float o = fmaxf(fmaf(acc[j], inv, bv[j]), 0.f);
            const ush h = f2bf(o);
            hh[j] = h;
            ll[j] = f2bf(o - bf2f(h));
        }
        *reinterpret_cast<ushx8*>(h1hi + (size_t)d * 128 + il * 8) = hh;
        *reinterpret_cast<ushx8*>(h1lo + (size_t)d * 128 + il * 8) = ll;
    }
}

// ---------- fused per-dst softmax aggregation, H=1 (64 cols, xl bf16) ----------
__global__ __launch_bounds__(256) void gat_dst1_k(
    const ush* __restrict__ xl, const float* __restrict__ xr,
    const int* __restrict__ row_ptr, const int* __restrict__ csr_src,
    const int* __restrict__ order, const float* __restrict__ att,
    const float* __restrict__ bias, float* __restrict__ out, int n) {
    const int lane = threadIdx.x & 63;
    const int g = lane >> 3, il = lane & 7;
    const int w = (blockIdx.x * blockDim.x + threadIdx.x) >> 6;
    if (w >= n) return;
    const int d = order[w];

    float xv[8], av[8];
    {
        const float4* xp = reinterpret_cast<const float4*>(xr + (size_t)d * 64 + il * 8);
        const float4* ap = reinterpret_cast<const float4*>(att + il * 8);
        const float4 x0 = xp[0], x1 = xp[1], a0 = ap[0], a1 = ap[1];
        xv[0]=x0.x; xv[1]=x0.y; xv[2]=x0.z; xv[3]=x0.w;
        xv[4]=x1.x; xv[5]=x1.y; xv[6]=x1.z; xv[7]=x1.w;
        av[0]=a0.x; av[1]=a0.y; av[2]=a0.z; av[3]=a0.w;
        av[4]=a1.x; av[5]=a1.y; av[6]=a1.z; av[7]=a1.w;
    }
    const int rp0 = row_ptr[d], rp1 = row_ptr[d + 1];

    float s = 0.f;
    float acc[8] = {0.f, 0.f, 0.f, 0.f, 0.f, 0.f, 0.f, 0.f};
    int i = rp0 + g;
    for (; i + 8 < rp1; i += 16) {
        const int s0 = csr_src[i];
        const int s1 = csr_src[i + 8];
        const ushx8 u0 = *reinterpret_cast<const ushx8*>(xl + (((size_t)(unsigned)s0) << 6) + il * 8);
        const ushx8 u1 = *reinterpret_cast<const ushx8*>(xl + (((size_t)(unsigned)s1) << 6) + il * 8);
        float f0[8], f1[8], p0 = 0.f, p1 = 0.f;
#pragma unroll
        for (int j = 0; j < 8; ++j) {
            f0[j] = bf2f((ush)u0[j]);
            const float v = f0[j] + xv[j];
            p0 = fmaf(av[j], fmaxf(v, 0.2f * v), p0);
        }
#pragma unroll
        for (int j = 0; j < 8; ++j) {
            f1[j] = bf2f((ush)u1[j]);
            const float v = f1[j] + xv[j];
            p1 = fmaf(av[j], fmaxf(v, 0.2f * v), p1);
        }
        p0 += __shfl_xor(p0, 4, 64); p0 += __shfl_xor(p0, 2, 64); p0 += __shfl_xor(p0, 1, 64);
        p1 += __shfl_xor(p1, 4, 64); p1 += __shfl_xor(p1, 2, 64); p1 += __shfl_xor(p1, 1, 64);
        const float w0 = __expf(p0), w1 = __expf(p1);
        s += w0 + w1;
#pragma unroll
        for (int j = 0; j < 8; ++j) acc[j] = fmaf(w0, f0[j], fmaf(w1, f1[j], acc[j]));
    }
    if (i < rp1) {
        const int s0 = csr_src[i];
        const ushx8 u0 = *reinterpret_cast<const ushx8*>(xl + (((size_t)(unsigned)s0) << 6) + il * 8);
        float f0[8], p0 = 0.f;
#pragma unroll
        for (int j = 0; j < 8; ++j) {
            f0[j] = bf2f((ush)u0[j]);
            const float v = f0[j] + xv[j];
            p0 = fmaf(av[j], fmaxf(v, 0.2f * v), p0);
        }
        p0 += __shfl_xor(p0, 4, 64); p0 += __shfl_xor(p0, 2, 64); p0 += __shfl_xor(p0, 1, 64);
        const float w0 = __expf(p0);
        s += w0;
#pragma unroll
        for (int j = 0; j < 8; ++j) acc[j] = fmaf(w0, f0[j], acc[j]);
    }
#pragma unroll
    for (int off = 8; off <= 32; off <<= 1) {
        s += __shfl_xor(s, off, 64);
#pragma unroll
        for (int j = 0; j < 8; ++j) acc[j] += __shfl_xor(acc[j], off, 64);
    }
    if (g == 0) {
        const float inv = 1.f / (s + 1e-16f);
        float bv[8];
        {
            const float4* bp = reinterpret_cast<const float4*>(bias + il * 8);
            const float4 b0 = bp[0], b1 = bp[1];
            bv[0]=b0.x; bv[1]=b0.y; bv[2]=b0.z; bv[3]=b0.w;
            bv[4]=b1.x; bv[5]=b1.y; bv[6]=b1.z; bv[7]=b1.w;
        }
        float4 o0, o1;
        o0.x = fmaxf(fmaf(acc[0], inv, bv[0]), 0.f);
        o0.y = fmaxf(fmaf(acc[1], inv, bv[1]), 0.f);
        o0.z = fmaxf(fmaf(acc[2], inv, bv[2]), 0.f);
        o0.w = fmaxf(fmaf(acc[3], inv, bv[3]), 0.f);
        o1.x = fmaxf(fmaf(acc[4], inv, bv[4]), 0.f);
        o1.y = fmaxf(fmaf(acc[5], inv, bv[5]), 0.f);
        o1.z = fmaxf(fmaf(acc[6], inv, bv[6]), 0.f);
        o1.w = fmaxf(fmaf(acc[7], inv, bv[7]), 0.f);
        float4* op = reinterpret_cast<float4*>(out + (size_t)d * 64 + il * 8);
        op[0] = o0;
        op[1] = o1;
    }
}

extern "C" void kernel_launch(void* const* d_in, const int* in_sizes, int n_in,
                              void* d_out, int out_size, void* d_ws, size_t ws_size,
                              hipStream_t stream) {
    const float* x    = (const float*)d_in[0];
    const int*   ei   = (const int*)d_in[1];
    const float* Wl1  = (const float*)d_in[2];
    const float* Wr1  = (const float*)d_in[3];
    const float* att1 = (const float*)d_in[4];
    const float* b1   = (const float*)d_in[5];
    const float* Wl2  = (const float*)d_in[6];
    const float* Wr2  = (const float*)d_in[7];
    const float* att2 = (const float*)d_in[8];
    const float* b2   = (const float*)d_in[9];

    const int n    = in_sizes[0] / 128;   // 50000
    const int e0   = in_sizes[1] / 2;     // 800000
    const int etot = e0 + n;
    const int* srcs = ei;
    const int* dsts = ei + e0;

    float* ws = (float*)d_ws;
    ush*   h1hi = (ush*)ws;                        // n*128 ush
    ush*   h1lo = (ush*)(ws + (size_t)n * 64);     // n*128 ush
    ush*   xlbf = (ush*)(ws + (size_t)n * 128);    // n*128 ush
    float* xr   = ws + (size_t)n * 192;            // n*128 f32
    int* row_ptr = (int*)(ws + (size_t)n * 320);   // n+2
    int* ghist   = row_ptr + (n + 2);              // 512
    int* cur     = ghist + 512;                    // 512
    int* dbin    = cur + 512;                      // 128
    int* dcur    = dbin + 128;                     // 128
    int* order   = dcur + 128;                     // n
    int* csr_src = order + n;                      // etot
    int* pairs   = csr_src + etot;                 // etot (packed)
    ush* wph     = (ush*)(pairs + etot);           // 96*512 ush
    ush* wpl     = wph + 96 * 512;                 // 96*512 ush

    const int NB    = (n + 127) / 128;             // 391 <= 512
    const int NDB   = (n + 255) / 256;             // 196
    const int nblka = (etot + 2047) / 2048;        // 416
    const int g1    = (n + 15) / 16;               // 3125 (gemm1: 16 rows/block)
    const int g2    = (n + 31) / 32;               // 1563 (gemm2: 32 rows/block)

    // 1) zero ghist + cur + dbin + dcur
    hipMemsetAsync(ghist, 0, 1280 * sizeof(int), stream);
    // 2) hist (256 blocks) + prep_w (24 blocks)
    fusedA_k<<<256 + 24, 256, 0, stream>>>(dsts, ghist, Wl1, Wr1, Wl2, Wr2,
                                           wph, wpl, e0, etot);
    // 3) semisort (nblka blocks) + layer-1 GEMM (g1 blocks)
    fusedB_k<<<nblka + g1, 256, 0, stream>>>(
        srcs, dsts, ghist, cur, pairs, x,
        wph, wpl, wph + 32 * 512, wpl + 32 * 512, xlbf, xr,
        e0, etot, nblka, n);
    // 4) row_ptr + csr_src + global degree hist
    bucket_fill2_k<<<NB, 256, 0, stream>>>(pairs, ghist, row_ptr, csr_src,
                                           dbin, n, etot);
    // 5) global degree order (scan folded in)
    deg_scatter2_k<<<NDB, 256, 0, stream>>>(row_ptr, dbin, dcur, order, n);
    // 6) layer-1 attention
    gat_dst2_k<<<(n + 3) / 4, 256, 0, stream>>>(xlbf, xr, row_ptr, csr_src, order,
                                                att1, b1, h1hi, h1lo, n);
    // 7) layer-2 GEMM
    gemm2_k<<<g2, 256, 0, stream>>>(h1hi, h1lo, wph + 64 * 512, wpl + 64 * 512,
                                    wph + 80 * 512, wpl + 80 * 512, xlbf, xr, n);
    // 8) layer-2 attention
    gat_dst1_k<<<(n + 3) / 4, 256, 0, stream>>>(xlbf, xr, row_ptr, csr_src, order,
                                                att2, b2, (float*)d_out, n);
}

// Round 21
// 175.888 us; speedup vs baseline: 1.0790x; 1.0468x over previous
//
#include <hip/hip_runtime.h>
#include <math.h>

typedef unsigned short ush;
typedef short bf16x8 __attribute__((ext_vector_type(8)));
typedef float f32x4 __attribute__((ext_vector_type(4)));
typedef ush ushx8 __attribute__((ext_vector_type(8)));

// ---------- bf16 helpers ----------
__device__ __forceinline__ ush f2bf(float f) {
    unsigned u = __float_as_uint(f);
    u += 0x7FFFu + ((u >> 16) & 1u);
    return (ush)(u >> 16);
}
__device__ __forceinline__ float bf2f(ush u) {
    return __uint_as_float((unsigned)u << 16);
}

// ================= fused A: hist (blocks 0..255) + prep_w (blocks 256..279) ====
__global__ __launch_bounds__(256) void fusedA_k(
    const int* __restrict__ dsts, int* __restrict__ ghist,
    const float* __restrict__ Wl1, const float* __restrict__ Wr1,
    const float* __restrict__ Wl2, const float* __restrict__ Wr2,
    ush* __restrict__ wph, ush* __restrict__ wpl, int e0, int etot) {
    const int t = threadIdx.x;
    if (blockIdx.x < 256) {
        __shared__ int h[512];
        for (int i = t; i < 512; i += 256) h[i] = 0;
        __syncthreads();
        for (int i = blockIdx.x * 256 + t; i < etot; i += 256 * 256) {
            const int d = (i < e0) ? dsts[i] : (i - e0);
            atomicAdd(&h[d >> 7], 1);
        }
        __syncthreads();
        for (int i = t; i < 512; i += 256)
            if (h[i]) atomicAdd(&ghist[i], h[i]);
    } else {
        const int bid = (blockIdx.x - 256) * 4 + (t >> 6);
        const int l = t & 63;
        const float* W;
        int C, fid;
        if (bid < 32)      { W = Wl1; C = 128; fid = bid; }
        else if (bid < 64) { W = Wr1; C = 128; fid = bid - 32; }
        else if (bid < 80) { W = Wl2; C = 64;  fid = bid - 64; }
        else               { W = Wr2; C = 64;  fid = bid - 80; }
        const int nc16 = C / 16;
        const int ks = fid / nc16, c16 = fid % nc16;
#pragma unroll
        for (int j = 0; j < 8; ++j) {
            const int k = ks * 32 + (l >> 4) * 8 + j;
            const int c = c16 * 16 + (l & 15);
            const float v = W[(size_t)k * C + c];
            const ush h = f2bf(v);
            wph[(size_t)(bid * 64 + l) * 8 + j] = h;
            wpl[(size_t)(bid * 64 + l) * 8 + j] = f2bf(v - bf2f(h));
        }
    }
}

// ================= fused B: semisort (blocks < nblka, 4096 edges/block) + gemm1
__global__ __launch_bounds__(256) void fusedB_k(
    const int* __restrict__ srcs, const int* __restrict__ dsts,
    const int* __restrict__ ghist, int* __restrict__ cur, int* __restrict__ pairs,
    const float* __restrict__ x,
    const ush* __restrict__ wh1, const ush* __restrict__ wl1,
    const ush* __restrict__ wh2, const ush* __restrict__ wl2,
    ush* __restrict__ ybf, float* __restrict__ yf,
    int e0, int etot, int nblka, int n) {
    const int t = threadIdx.x;
    if ((int)blockIdx.x < nblka) {
        __shared__ int sb[512];
        __shared__ int red[256];
        __shared__ int hist[512], gbase[512], lcur[512];
        const int a0 = ghist[2 * t], a1 = ghist[2 * t + 1];
        red[t] = a0 + a1;
        __syncthreads();
#pragma unroll
        for (int s = 1; s < 256; s <<= 1) {
            const int add = (t >= s) ? red[t - s] : 0;
            __syncthreads();
            red[t] += add;
            __syncthreads();
        }
        const int base = red[t] - a0 - a1;
        sb[2 * t] = base;
        sb[2 * t + 1] = base + a0;
        for (int i = t; i < 512; i += 256) { hist[i] = 0; lcur[i] = 0; }
        __syncthreads();
        const int start = blockIdx.x * 4096;
        const int end = min(start + 4096, etot);
        for (int i = start + t; i < end; i += 256) {
            const int d = (i < e0) ? dsts[i] : (i - e0);
            atomicAdd(&hist[d >> 7], 1);
        }
        __syncthreads();
        for (int i = t; i < 512; i += 256) {
            const int c = hist[i];
            gbase[i] = c ? (sb[i] + atomicAdd(&cur[i], c)) : 0;
        }
        __syncthreads();
        for (int i = start + t; i < end; i += 256) {
            int s, d;
            if (i < e0) { s = srcs[i]; d = dsts[i]; } else { s = d = i - e0; }
            const int b = d >> 7;
            const int p = atomicAdd(&lcur[b], 1);
            pairs[gbase[b] + p] = s | ((d & 127) << 24);
        }
    } else {
        const int l = t & 63;
        const int w = t >> 6;                 // wave = output slab
        const int r0 = ((int)blockIdx.x - nblka) * 16;
        const int arow = min(r0 + (l & 15), n - 1);
        const int kb = (l >> 4) * 8;
        bf16x8 ah[4], al[4];
#pragma unroll
        for (int ks = 0; ks < 4; ++ks) {
            const float* ap = x + (size_t)arow * 128 + ks * 32 + kb;
            const float4 v0 = *reinterpret_cast<const float4*>(ap);
            const float4 v1 = *reinterpret_cast<const float4*>(ap + 4);
            const float fv[8] = {v0.x, v0.y, v0.z, v0.w, v1.x, v1.y, v1.z, v1.w};
#pragma unroll
            for (int j = 0; j < 8; ++j) {
                const ush h = f2bf(fv[j]);
                ah[ks][j] = (short)h;
                al[ks][j] = (short)f2bf(fv[j] - bf2f(h));
            }
        }
        const bool isW1 = w < 2;
        const int sl = w & 1;
        const ush* __restrict__ wh = isW1 ? wh1 : wh2;
        const ush* __restrict__ wl = isW1 ? wl1 : wl2;
        const int drow = (l >> 4) * 4;
        const int dcol = l & 15;
        f32x4 acc[4];
#pragma unroll
        for (int c16 = 0; c16 < 4; ++c16) acc[c16] = {0.f, 0.f, 0.f, 0.f};
#pragma unroll
        for (int ks = 0; ks < 4; ++ks) {
            bf16x8 bh[4], bl[4];
#pragma unroll
            for (int c16 = 0; c16 < 4; ++c16) {
                const int fid = ks * 8 + sl * 4 + c16;
                bh[c16] = *reinterpret_cast<const bf16x8*>(wh + (size_t)(fid * 64 + l) * 8);
                bl[c16] = *reinterpret_cast<const bf16x8*>(wl + (size_t)(fid * 64 + l) * 8);
            }
#pragma unroll
            for (int c16 = 0; c16 < 4; ++c16)
                acc[c16] = __builtin_amdgcn_mfma_f32_16x16x32_bf16(ah[ks], bh[c16], acc[c16], 0, 0, 0);
#pragma unroll
            for (int c16 = 0; c16 < 4; ++c16)
                acc[c16] = __builtin_amdgcn_mfma_f32_16x16x32_bf16(al[ks], bh[c16], acc[c16], 0, 0, 0);
#pragma unroll
            for (int c16 = 0; c16 < 4; ++c16)
                acc[c16] = __builtin_amdgcn_mfma_f32_16x16x32_bf16(ah[ks], bl[c16], acc[c16], 0, 0, 0);
        }
#pragma unroll
        for (int c16 = 0; c16 < 4; ++c16) {
            const int cg = sl * 64 + c16 * 16 + dcol;
#pragma unroll
            for (int q = 0; q < 4; ++q) {
                const int gr = r0 + drow + q;
                if (gr < n) {
                    if (isW1) ybf[(size_t)gr * 128 + cg] = f2bf(acc[c16][q]);
                    else      yf[(size_t)gr * 128 + cg] = acc[c16][q];
                }
            }
        }
    }
}

// ===== bucket_fill2: row_ptr + csr fill + global degree histogram ======
__global__ __launch_bounds__(256) void bucket_fill2_k(
    const int* __restrict__ pairs, const int* __restrict__ ghist,
    int* __restrict__ row_ptr, int* __restrict__ csr_src,
    int* __restrict__ dbin, int n, int etot) {
    __shared__ int sb[512];
    __shared__ int red[256];
    __shared__ int cnt[128], cur[128], hcnt[128];
    const int b = blockIdx.x, t = threadIdx.x;
    const int a0 = ghist[2 * t], a1 = ghist[2 * t + 1];
    red[t] = a0 + a1;
    __syncthreads();
#pragma unroll
    for (int s = 1; s < 256; s <<= 1) {
        const int add = (t >= s) ? red[t - s] : 0;
        __syncthreads();
        red[t] += add;
        __syncthreads();
    }
    const int base = red[t] - a0 - a1;
    sb[2 * t] = base;
    sb[2 * t + 1] = base + a0;
    if (t < 128) { cnt[t] = 0; hcnt[t] = 0; }
    __syncthreads();
    const int lo = sb[b];
    const int hi = (b + 1 < 512) ? sb[b + 1] : etot;
    for (int e = lo + t; e < hi; e += 256)
        atomicAdd(&cnt[(pairs[e] >> 24) & 127], 1);
    __syncthreads();
    const int x = (t < 128) ? cnt[t] : 0;
#pragma unroll
    for (int s = 1; s < 128; s <<= 1) {
        const int add = (t < 128 && t >= s) ? cnt[t - s] : 0;
        __syncthreads();
        if (t < 128) cnt[t] += add;
        __syncthreads();
    }
    if (t < 128) {
        const int excl = cnt[t] - x;
        cur[t] = excl;
        const int d = b * 128 + t;
        if (d < n) {
            row_ptr[d] = lo + excl;
            atomicAdd(&hcnt[127 - min(x, 127)], 1);
        }
    }
    if (b == 0 && t == 0) row_ptr[n] = etot;
    __syncthreads();
    if (t < 128 && hcnt[t]) atomicAdd(&dbin[t], hcnt[t]);
    for (int e = lo + t; e < hi; e += 256) {
        const int p = pairs[e];
        const int pos = atomicAdd(&cur[(p >> 24) & 127], 1);
        csr_src[lo + pos] = p & 0xFFFFFF;
    }
}

// ---- global degree order: local scan of dbin + zeroed global cursor ----
__global__ __launch_bounds__(256) void deg_scatter2_k(
    const int* __restrict__ row_ptr, const int* __restrict__ dbin,
    int* __restrict__ dcur, int* __restrict__ order, int n) {
    __shared__ int excl[128], red[128];
    __shared__ int h[128], gbase[128], lcur[128];
    const int t = threadIdx.x;
    if (t < 128) red[t] = dbin[t];
    __syncthreads();
#pragma unroll
    for (int s = 1; s < 128; s <<= 1) {
        const int add = (t < 128 && t >= s) ? red[t - s] : 0;
        __syncthreads();
        if (t < 128) red[t] += add;
        __syncthreads();
    }
    if (t < 128) {
        excl[t] = red[t] - dbin[t];
        h[t] = 0;
        lcur[t] = 0;
    }
    __syncthreads();
    const int d = blockIdx.x * 256 + t;
    int bin = -1;
    if (d < n) {
        const int deg = row_ptr[d + 1] - row_ptr[d];
        bin = 127 - min(deg, 127);
        atomicAdd(&h[bin], 1);
    }
    __syncthreads();
    if (t < 128) gbase[t] = h[t] ? (excl[t] + atomicAdd(&dcur[t], h[t])) : 0;
    __syncthreads();
    if (d < n) {
        const int p = atomicAdd(&lcur[bin], 1);
        order[gbase[bin] + p] = d;
    }
}

// ---------- layer-2 MFMA GEMM: 32 rows/block, wave = (slab,rowhalf) ----------
__global__ __launch_bounds__(256) void gemm2_k(
    const ush* __restrict__ ahi, const ush* __restrict__ alo,
    const ush* __restrict__ whl, const ush* __restrict__ wll,
    const ush* __restrict__ whr, const ush* __restrict__ wlr,
    ush* __restrict__ ybf, float* __restrict__ yf, int n) {
    const int l = threadIdx.x & 63;
    const int w = threadIdx.x >> 6;
    const int slab = w >> 1, rh = w & 1;
    const int r0 = blockIdx.x * 32 + rh * 16;
    const int arow = min(r0 + (l & 15), n - 1);
    const int kb = (l >> 4) * 8;
    bf16x8 ah[4], al[4];
#pragma unroll
    for (int ks = 0; ks < 4; ++ks) {
        ah[ks] = *reinterpret_cast<const bf16x8*>(ahi + (size_t)arow * 128 + ks * 32 + kb);
        al[ks] = *reinterpret_cast<const bf16x8*>(alo + (size_t)arow * 128 + ks * 32 + kb);
    }
    const ush* __restrict__ wh = slab ? whr : whl;
    const ush* __restrict__ wl = slab ? wlr : wll;
    const int drow = (l >> 4) * 4;
    const int dcol = l & 15;
    f32x4 acc[4];
#pragma unroll
    for (int c16 = 0; c16 < 4; ++c16) acc[c16] = {0.f, 0.f, 0.f, 0.f};
#pragma unroll
    for (int ks = 0; ks < 4; ++ks) {
        bf16x8 bh[4], bl[4];
#pragma unroll
        for (int c16 = 0; c16 < 4; ++c16) {
            const int fid = ks * 4 + c16;
            bh[c16] = *reinterpret_cast<const bf16x8*>(wh + (size_t)(fid * 64 + l) * 8);
            bl[c16] = *reinterpret_cast<const bf16x8*>(wl + (size_t)(fid * 64 + l) * 8);
        }
#pragma unroll
        for (int c16 = 0; c16 < 4; ++c16)
            acc[c16] = __builtin_amdgcn_mfma_f32_16x16x32_bf16(ah[ks], bh[c16], acc[c16], 0, 0, 0);
#pragma unroll
        for (int c16 = 0; c16 < 4; ++c16)
            acc[c16] = __builtin_amdgcn_mfma_f32_16x16x32_bf16(al[ks], bh[c16], acc[c16], 0, 0, 0);
#pragma unroll
        for (int c16 = 0; c16 < 4; ++c16)
            acc[c16] = __builtin_amdgcn_mfma_f32_16x16x32_bf16(ah[ks], bl[c16], acc[c16], 0, 0, 0);
    }
#pragma unroll
    for (int c16 = 0; c16 < 4; ++c16) {
        const int cg = c16 * 16 + dcol;
#pragma unroll
        for (int q = 0; q < 4; ++q) {
            const int gr = r0 + drow + q;
            if (gr < n) {
                if (slab == 0) ybf[(size_t)gr * 64 + cg] = f2bf(acc[c16][q]);
                else           yf[(size_t)gr * 64 + cg] = acc[c16][q];
            }
        }
    }
}

// ---------- fused per-dst softmax aggregation, H=2 (128 cols, xl bf16) ----------
__global__ __launch_bounds__(256) void gat_dst2_k(
    const ush* __restrict__ xl, const float* __restrict__ xr,
    const int* __restrict__ row_ptr, const int* __restrict__ csr_src,
    const int* __restrict__ order, const float* __restrict__ att,
    const float* __restrict__ bias, ush* __restrict__ h1hi,
    ush* __restrict__ h1lo, int n) {
    const int lane = threadIdx.x & 63;
    const int g = lane >> 4, il = lane & 15;
    const int w = (blockIdx.x * blockDim.x + threadIdx.x) >> 6;
    if (w >= n) return;
    const int d = order[w];

    float xv[8], av[8];
    {
        const float4* xp = reinterpret_cast<const float4*>(xr + (size_t)d * 128 + il * 8);
        const float4* ap = reinterpret_cast<const float4*>(att + il * 8);
        const float4 x0 = xp[0], x1 = xp[1], a0 = ap[0], a1 = ap[1];
        xv[0]=x0.x; xv[1]=x0.y; xv[2]=x0.z; xv[3]=x0.w;
        xv[4]=x1.x; xv[5]=x1.y; xv[6]=x1.z; xv[7]=x1.w;
        av[0]=a0.x; av[1]=a0.y; av[2]=a0.z; av[3]=a0.w;
        av[4]=a1.x; av[5]=a1.y; av[6]=a1.z; av[7]=a1.w;
    }
    const int rp0 = row_ptr[d], rp1 = row_ptr[d + 1];

    float s = 0.f;
    float acc[8] = {0.f, 0.f, 0.f, 0.f, 0.f, 0.f, 0.f, 0.f};
    int i = rp0 + g;
    for (; i + 4 < rp1; i += 8) {
        const int s0 = csr_src[i];
        const int s1 = csr_src[i + 4];
        const ushx8 u0 = *reinterpret_cast<const ushx8*>(xl + (((size_t)(unsigned)s0) << 7) + il * 8);
        const ushx8 u1 = *reinterpret_cast<const ushx8*>(xl + (((size_t)(unsigned)s1) << 7) + il * 8);
        float f0[8], f1[8], p0 = 0.f, p1 = 0.f;
#pragma unroll
        for (int j = 0; j < 8; ++j) {
            f0[j] = bf2f((ush)u0[j]);
            const float v = f0[j] + xv[j];
            p0 = fmaf(av[j], fmaxf(v, 0.2f * v), p0);
        }
#pragma unroll
        for (int j = 0; j < 8; ++j) {
            f1[j] = bf2f((ush)u1[j]);
            const float v = f1[j] + xv[j];
            p1 = fmaf(av[j], fmaxf(v, 0.2f * v), p1);
        }
        p0 += __shfl_xor(p0, 4, 64); p0 += __shfl_xor(p0, 2, 64); p0 += __shfl_xor(p0, 1, 64);
        p1 += __shfl_xor(p1, 4, 64); p1 += __shfl_xor(p1, 2, 64); p1 += __shfl_xor(p1, 1, 64);
        const float w0 = __expf(p0), w1 = __expf(p1);
        s += w0 + w1;
#pragma unroll
        for (int j = 0; j < 8; ++j) acc[j] = fmaf(w0, f0[j], fmaf(w1, f1[j], acc[j]));
    }
    if (i < rp1) {
        const int s0 = csr_src[i];
        const ushx8 u0 = *reinterpret_cast<const ushx8*>(xl + (((size_t)(unsigned)s0) << 7) + il * 8);
        float f0[8], p0 = 0.f;
#pragma unroll
        for (int j = 0; j < 8; ++j) {
            f0[j] = bf2f((ush)u0[j]);
            const float v = f0[j] + xv[j];
            p0 = fmaf(av[j], fmaxf(v, 0.2f * v), p0);
        }
        p0 += __shfl_xor(p0, 4, 64); p0 += __shfl_xor(p0, 2, 64); p0 += __shfl_xor(p0, 1, 64);
        const float w0 = __expf(p0);
        s += w0;
#pragma unroll
        for (int j = 0; j < 8; ++j) acc[j] = fmaf(w0, f0[j], acc[j]);
    }
#pragma unroll
    for (int off = 16; off <= 32; off <<= 1) {
        s += __shfl_xor(s, off, 64);
#pragma unroll
        for (int j = 0; j < 8; ++j) acc[j] += __shfl_xor(acc[j], off, 64);
    }
    if (g == 0) {
        const float inv = 1.f / (s + 1e-16f);
        float bv[8];
        {
            const float4* bp = reinterpret_cast<const float4*>(bias + il * 8);
            const float4 b0 = bp[0], b1 = bp[1];
            bv[0]=b0.x; bv[1]=b0.y; bv[2]=b0.z; bv[3]=b0.w;
            bv[4]=b1.x; bv[5]=b1.y; bv[6]=b1.z; bv[7]=b1.w;
        }
        ushx8 hh, ll;
#pragma unroll
        for (int j = 0; j < 8; ++j) {
            const float o = fmaxf(fmaf(acc[j], inv, bv[j]), 0.f);
            const ush h = f2bf(o);
            hh[j] = h;
            ll[j] = f2bf(o - bf2f(h));
        }
        *reinterpret_cast<ushx8*>(h1hi + (size_t)d * 128 + il * 8) = hh;
        *reinterpret_cast<ushx8*>(h1lo + (size_t)d * 128 + il * 8) = ll;
    }
}

// ---------- fused per-dst softmax aggregation, H=1 (64 cols, xl bf16) ----------
__global__ __launch_bounds__(256) void gat_dst1_k(
    const ush* __restrict__ xl, const float* __restrict__ xr,
    const int* __restrict__ row_ptr, const int* __restrict__ csr_src,
    const int* __restrict__ order, const float* __restrict__ att,
    const float* __restrict__ bias, float* __restrict__ out, int n) {
    const int lane = threadIdx.x & 63;
    const int g = lane >> 3, il = lane & 7;
    const int w = (blockIdx.x * blockDim.x + threadIdx.x) >> 6;
    if (w >= n) return;
    const int d = order[w];

    float xv[8], av[8];
    {
        const float4* xp = reinterpret_cast<const float4*>(xr + (size_t)d * 64 + il * 8);
        const float4* ap = reinterpret_cast<const float4*>(att + il * 8);
        const float4 x0 = xp[0], x1 = xp[1], a0 = ap[0], a1 = ap[1];
        xv[0]=x0.x; xv[1]=x0.y; xv[2]=x0.z; xv[3]=x0.w;
        xv[4]=x1.x; xv[5]=x1.y; xv[6]=x1.z; xv[7]=x1.w;
        av[0]=a0.x; av[1]=a0.y; av[2]=a0.z; av[3]=a0.w;
        av[4]=a1.x; av[5]=a1.y; av[6]=a1.z; av[7]=a1.w;
    }
    const int rp0 = row_ptr[d], rp1 = row_ptr[d + 1];

    float s = 0.f;
    float acc[8] = {0.f, 0.f, 0.f, 0.f, 0.f, 0.f, 0.f, 0.f};
    int i = rp0 + g;
    for (; i + 8 < rp1; i += 16) {
        const int s0 = csr_src[i];
        const int s1 = csr_src[i + 8];
        const ushx8 u0 = *reinterpret_cast<const ushx8*>(xl + (((size_t)(unsigned)s0) << 6) + il * 8);
        const ushx8 u1 = *reinterpret_cast<const ushx8*>(xl + (((size_t)(unsigned)s1) << 6) + il * 8);
        float f0[8], f1[8], p0 = 0.f, p1 = 0.f;
#pragma unroll
        for (int j = 0; j < 8; ++j) {
            f0[j] = bf2f((ush)u0[j]);
            const float v = f0[j] + xv[j];
            p0 = fmaf(av[j], fmaxf(v, 0.2f * v), p0);
        }
#pragma unroll
        for (int j = 0; j < 8; ++j) {
            f1[j] = bf2f((ush)u1[j]);
            const float v = f1[j] + xv[j];
            p1 = fmaf(av[j], fmaxf(v, 0.2f * v), p1);
        }
        p0 += __shfl_xor(p0, 4, 64); p0 += __shfl_xor(p0, 2, 64); p0 += __shfl_xor(p0, 1, 64);
        p1 += __shfl_xor(p1, 4, 64); p1 += __shfl_xor(p1, 2, 64); p1 += __shfl_xor(p1, 1, 64);
        const float w0 = __expf(p0), w1 = __expf(p1);
        s += w0 + w1;
#pragma unroll
        for (int j = 0; j < 8; ++j) acc[j] = fmaf(w0, f0[j], fmaf(w1, f1[j], acc[j]));
    }
    if (i < rp1) {
        const int s0 = csr_src[i];
        const ushx8 u0 = *reinterpret_cast<const ushx8*>(xl + (((size_t)(unsigned)s0) << 6) + il * 8);
        float f0[8], p0 = 0.f;
#pragma unroll
        for (int j = 0; j < 8; ++j) {
            f0[j] = bf2f((ush)u0[j]);
            const float v = f0[j] + xv[j];
            p0 = fmaf(av[j], fmaxf(v, 0.2f * v), p0);
        }
        p0 += __shfl_xor(p0, 4, 64); p0 += __shfl_xor(p0, 2, 64); p0 += __shfl_xor(p0, 1, 64);
        const float w0 = __expf(p0);
        s += w0;
#pragma unroll
        for (int j = 0; j < 8; ++j) acc[j] = fmaf(w0, f0[j], acc[j]);
    }
#pragma unroll
    for (int off = 8; off <= 32; off <<= 1) {
        s += __shfl_xor(s, off, 64);
#pragma unroll
        for (int j = 0; j < 8; ++j) acc[j] += __shfl_xor(acc[j], off, 64);
    }
    if (g == 0) {
        const float inv = 1.f / (s + 1e-16f);
        float bv[8];
        {
            const float4* bp = reinterpret_cast<const float4*>(bias + il * 8);
            const float4 b0 = bp[0], b1 = bp[1];
            bv[0]=b0.x; bv[1]=b0.y; bv[2]=b0.z; bv[3]=b0.w;
            bv[4]=b1.x; bv[5]=b1.y; bv[6]=b1.z; bv[7]=b1.w;
        }
        float4 o0, o1;
        o0.x = fmaxf(fmaf(acc[0], inv, bv[0]), 0.f);
        o0.y = fmaxf(fmaf(acc[1], inv, bv[1]), 0.f);
        o0.z = fmaxf(fmaf(acc[2], inv, bv[2]), 0.f);
        o0.w = fmaxf(fmaf(acc[3], inv, bv[3]), 0.f);
        o1.x = fmaxf(fmaf(acc[4], inv, bv[4]), 0.f);
        o1.y = fmaxf(fmaf(acc[5], inv, bv[5]), 0.f);
        o1.z = fmaxf(fmaf(acc[6], inv, bv[6]), 0.f);
        o1.w = fmaxf(fmaf(acc[7], inv, bv[7]), 0.f);
        float4* op = reinterpret_cast<float4*>(out + (size_t)d * 64 + il * 8);
        op[0] = o0;
        op[1] = o1;
    }
}

extern "C" void kernel_launch(void* const* d_in, const int* in_sizes, int n_in,
                              void* d_out, int out_size, void* d_ws, size_t ws_size,
                              hipStream_t stream) {
    const float* x    = (const float*)d_in[0];
    const int*   ei   = (const int*)d_in[1];
    const float* Wl1  = (const float*)d_in[2];
    const float* Wr1  = (const float*)d_in[3];
    const float* att1 = (const float*)d_in[4];
    const float* b1   = (const float*)d_in[5];
    const float* Wl2  = (const float*)d_in[6];
    const float* Wr2  = (const float*)d_in[7];
    const float* att2 = (const float*)d_in[8];
    const float* b2   = (const float*)d_in[9];

    const int n    = in_sizes[0] / 128;   // 50000
    const int e0   = in_sizes[1] / 2;     // 800000
    const int etot = e0 + n;
    const int* srcs = ei;
    const int* dsts = ei + e0;

    float* ws = (float*)d_ws;
    ush*   h1hi = (ush*)ws;                        // n*128 ush
    ush*   h1lo = (ush*)(ws + (size_t)n * 64);     // n*128 ush
    ush*   xlbf = (ush*)(ws + (size_t)n * 128);    // n*128 ush
    float* xr   = ws + (size_t)n * 192;            // n*128 f32
    int* row_ptr = (int*)(ws + (size_t)n * 320);   // n+2
    int* ghist   = row_ptr + (n + 2);              // 512
    int* cur     = ghist + 512;                    // 512
    int* dbin    = cur + 512;                      // 128
    int* dcur    = dbin + 128;                     // 128
    int* order   = dcur + 128;                     // n
    int* csr_src = order + n;                      // etot
    int* pairs   = csr_src + etot;                 // etot (packed)
    ush* wph     = (ush*)(pairs + etot);           // 96*512 ush
    ush* wpl     = wph + 96 * 512;                 // 96*512 ush

    const int NB    = (n + 127) / 128;             // 391 <= 512
    const int NDB   = (n + 255) / 256;             // 196
    const int nblka = (etot + 4095) / 4096;        // 208
    const int g1    = (n + 15) / 16;               // 3125
    const int g2    = (n + 31) / 32;               // 1563

    // 1) zero ghist + cur + dbin + dcur
    hipMemsetAsync(ghist, 0, 1280 * sizeof(int), stream);
    // 2) hist (256 blocks) + prep_w (24 blocks)
    fusedA_k<<<256 + 24, 256, 0, stream>>>(dsts, ghist, Wl1, Wr1, Wl2, Wr2,
                                           wph, wpl, e0, etot);
    // 3) semisort (208 blocks, 4096 edges each) + layer-1 GEMM (g1 blocks)
    fusedB_k<<<nblka + g1, 256, 0, stream>>>(
        srcs, dsts, ghist, cur, pairs, x,
        wph, wpl, wph + 32 * 512, wpl + 32 * 512, xlbf, xr,
        e0, etot, nblka, n);
    // 4) row_ptr + csr_src + global degree hist
    bucket_fill2_k<<<NB, 256, 0, stream>>>(pairs, ghist, row_ptr, csr_src,
                                           dbin, n, etot);
    // 5) global degree order (scan folded in)
    deg_scatter2_k<<<NDB, 256, 0, stream>>>(row_ptr, dbin, dcur, order, n);
    // 6) layer-1 attention
    gat_dst2_k<<<(n + 3) / 4, 256, 0, stream>>>(xlbf, xr, row_ptr, csr_src, order,
                                                att1, b1, h1hi, h1lo, n);
    // 7) layer-2 GEMM
    gemm2_k<<<g2, 256, 0, stream>>>(h1hi, h1lo, wph + 64 * 512, wpl + 64 * 512,
                                    wph + 80 * 512, wpl + 80 * 512, xlbf, xr, n);
    // 8) layer-2 attention
    gat_dst1_k<<<(n + 3) / 4, 256, 0, stream>>>(xlbf, xr, row_ptr, csr_src, order,
                                                att2, b2, (float*)d_out, n);
}

// Round 22
// 175.485 us; speedup vs baseline: 1.0815x; 1.0023x over previous
//
#include <hip/hip_runtime.h>
#include <math.h>

typedef unsigned short ush;
typedef short bf16x8 __attribute__((ext_vector_type(8)));
typedef float f32x4 __attribute__((ext_vector_type(4)));
typedef ush ushx8 __attribute__((ext_vector_type(8)));

// ---------- bf16 helpers ----------
__device__ __forceinline__ ush f2bf(float f) {
    unsigned u = __float_as_uint(f);
    u += 0x7FFFu + ((u >> 16) & 1u);
    return (ush)(u >> 16);
}
__device__ __forceinline__ float bf2f(ush u) {
    return __uint_as_float((unsigned)u << 16);
}

#define CHUNK 8192

// ================= fused A: hist (blocks 0..255) + prep_w (blocks 256..279) ====
__global__ __launch_bounds__(256) void fusedA_k(
    const int* __restrict__ dsts, int* __restrict__ ghist,
    const float* __restrict__ Wl1, const float* __restrict__ Wr1,
    const float* __restrict__ Wl2, const float* __restrict__ Wr2,
    ush* __restrict__ wph, ush* __restrict__ wpl, int e0, int etot) {
    const int t = threadIdx.x;
    if (blockIdx.x < 256) {
        __shared__ int h[512];
        for (int i = t; i < 512; i += 256) h[i] = 0;
        __syncthreads();
        for (int i = blockIdx.x * 256 + t; i < etot; i += 256 * 256) {
            const int d = (i < e0) ? dsts[i] : (i - e0);
            atomicAdd(&h[d >> 7], 1);
        }
        __syncthreads();
        for (int i = t; i < 512; i += 256)
            if (h[i]) atomicAdd(&ghist[i], h[i]);
    } else {
        const int bid = (blockIdx.x - 256) * 4 + (t >> 6);
        const int l = t & 63;
        const float* W;
        int C, fid;
        if (bid < 32)      { W = Wl1; C = 128; fid = bid; }
        else if (bid < 64) { W = Wr1; C = 128; fid = bid - 32; }
        else if (bid < 80) { W = Wl2; C = 64;  fid = bid - 64; }
        else               { W = Wr2; C = 64;  fid = bid - 80; }
        const int nc16 = C / 16;
        const int ks = fid / nc16, c16 = fid % nc16;
#pragma unroll
        for (int j = 0; j < 8; ++j) {
            const int k = ks * 32 + (l >> 4) * 8 + j;
            const int c = c16 * 16 + (l & 15);
            const float v = W[(size_t)k * C + c];
            const ush h = f2bf(v);
            wph[(size_t)(bid * 64 + l) * 8 + j] = h;
            wpl[(size_t)(bid * 64 + l) * 8 + j] = f2bf(v - bf2f(h));
        }
    }
}

// ================= fused B: semisort (blocks < nblka, CHUNK edges/block) + gemm1
__global__ __launch_bounds__(256) void fusedB_k(
    const int* __restrict__ srcs, const int* __restrict__ dsts,
    const int* __restrict__ ghist, int* __restrict__ cur, int* __restrict__ pairs,
    const float* __restrict__ x,
    const ush* __restrict__ wh1, const ush* __restrict__ wl1,
    const ush* __restrict__ wh2, const ush* __restrict__ wl2,
    ush* __restrict__ ybf, float* __restrict__ yf,
    int e0, int etot, int nblka, int n) {
    const int t = threadIdx.x;
    if ((int)blockIdx.x < nblka) {
        __shared__ int sb[512];
        __shared__ int red[256];
        __shared__ int hist[512], gbase[512], lcur[512];
        const int a0 = ghist[2 * t], a1 = ghist[2 * t + 1];
        red[t] = a0 + a1;
        __syncthreads();
#pragma unroll
        for (int s = 1; s < 256; s <<= 1) {
            const int add = (t >= s) ? red[t - s] : 0;
            __syncthreads();
            red[t] += add;
            __syncthreads();
        }
        const int base = red[t] - a0 - a1;
        sb[2 * t] = base;
        sb[2 * t + 1] = base + a0;
        for (int i = t; i < 512; i += 256) { hist[i] = 0; lcur[i] = 0; }
        __syncthreads();
        const int start = blockIdx.x * CHUNK;
        const int end = min(start + CHUNK, etot);
        for (int i = start + t; i < end; i += 256) {
            const int d = (i < e0) ? dsts[i] : (i - e0);
            atomicAdd(&hist[d >> 7], 1);
        }
        __syncthreads();
        for (int i = t; i < 512; i += 256) {
            const int c = hist[i];
            gbase[i] = c ? (sb[i] + atomicAdd(&cur[i], c)) : 0;
        }
        __syncthreads();
        for (int i = start + t; i < end; i += 256) {
            int s, d;
            if (i < e0) { s = srcs[i]; d = dsts[i]; } else { s = d = i - e0; }
            const int b = d >> 7;
            const int p = atomicAdd(&lcur[b], 1);
            pairs[gbase[b] + p] = s | ((d & 127) << 24);
        }
    } else {
        const int l = t & 63;
        const int w = t >> 6;                 // wave = output slab
        const int r0 = ((int)blockIdx.x - nblka) * 16;
        const int arow = min(r0 + (l & 15), n - 1);
        const int kb = (l >> 4) * 8;
        bf16x8 ah[4], al[4];
#pragma unroll
        for (int ks = 0; ks < 4; ++ks) {
            const float* ap = x + (size_t)arow * 128 + ks * 32 + kb;
            const float4 v0 = *reinterpret_cast<const float4*>(ap);
            const float4 v1 = *reinterpret_cast<const float4*>(ap + 4);
            const float fv[8] = {v0.x, v0.y, v0.z, v0.w, v1.x, v1.y, v1.z, v1.w};
#pragma unroll
            for (int j = 0; j < 8; ++j) {
                const ush h = f2bf(fv[j]);
                ah[ks][j] = (short)h;
                al[ks][j] = (short)f2bf(fv[j] - bf2f(h));
            }
        }
        const bool isW1 = w < 2;
        const int sl = w & 1;
        const ush* __restrict__ wh = isW1 ? wh1 : wh2;
        const ush* __restrict__ wl = isW1 ? wl1 : wl2;
        const int drow = (l >> 4) * 4;
        const int dcol = l & 15;
        f32x4 acc[4];
#pragma unroll
        for (int c16 = 0; c16 < 4; ++c16) acc[c16] = {0.f, 0.f, 0.f, 0.f};
#pragma unroll
        for (int ks = 0; ks < 4; ++ks) {
            bf16x8 bh[4], bl[4];
#pragma unroll
            for (int c16 = 0; c16 < 4; ++c16) {
                const int fid = ks * 8 + sl * 4 + c16;
                bh[c16] = *reinterpret_cast<const bf16x8*>(wh + (size_t)(fid * 64 + l) * 8);
                bl[c16] = *reinterpret_cast<const bf16x8*>(wl + (size_t)(fid * 64 + l) * 8);
            }
#pragma unroll
            for (int c16 = 0; c16 < 4; ++c16)
                acc[c16] = __builtin_amdgcn_mfma_f32_16x16x32_bf16(ah[ks], bh[c16], acc[c16], 0, 0, 0);
#pragma unroll
            for (int c16 = 0; c16 < 4; ++c16)
                acc[c16] = __builtin_amdgcn_mfma_f32_16x16x32_bf16(al[ks], bh[c16], acc[c16], 0, 0, 0);
#pragma unroll
            for (int c16 = 0; c16 < 4; ++c16)
                acc[c16] = __builtin_amdgcn_mfma_f32_16x16x32_bf16(ah[ks], bl[c16], acc[c16], 0, 0, 0);
        }
#pragma unroll
        for (int c16 = 0; c16 < 4; ++c16) {
            const int cg = sl * 64 + c16 * 16 + dcol;
#pragma unroll
            for (int q = 0; q < 4; ++q) {
                const int gr = r0 + drow + q;
                if (gr < n) {
                    if (isW1) ybf[(size_t)gr * 128 + cg] = f2bf(acc[c16][q]);
                    else      yf[(size_t)gr * 128 + cg] = acc[c16][q];
                }
            }
        }
    }
}

// ===== bucket_fill2: row_ptr + csr fill + global degree histogram ======
__global__ __launch_bounds__(256) void bucket_fill2_k(
    const int* __restrict__ pairs, const int* __restrict__ ghist,
    int* __restrict__ row_ptr, int* __restrict__ csr_src,
    int* __restrict__ dbin, int n, int etot) {
    __shared__ int sb[512];
    __shared__ int red[256];
    __shared__ int cnt[128], cur[128], hcnt[128];
    const int b = blockIdx.x, t = threadIdx.x;
    const int a0 = ghist[2 * t], a1 = ghist[2 * t + 1];
    red[t] = a0 + a1;
    __syncthreads();
#pragma unroll
    for (int s = 1; s < 256; s <<= 1) {
        const int add = (t >= s) ? red[t - s] : 0;
        __syncthreads();
        red[t] += add;
        __syncthreads();
    }
    const int base = red[t] - a0 - a1;
    sb[2 * t] = base;
    sb[2 * t + 1] = base + a0;
    if (t < 128) { cnt[t] = 0; hcnt[t] = 0; }
    __syncthreads();
    const int lo = sb[b];
    const int hi = (b + 1 < 512) ? sb[b + 1] : etot;
    for (int e = lo + t; e < hi; e += 256)
        atomicAdd(&cnt[(pairs[e] >> 24) & 127], 1);
    __syncthreads();
    const int x = (t < 128) ? cnt[t] : 0;
#pragma unroll
    for (int s = 1; s < 128; s <<= 1) {
        const int add = (t < 128 && t >= s) ? cnt[t - s] : 0;
        __syncthreads();
        if (t < 128) cnt[t] += add;
        __syncthreads();
    }
    if (t < 128) {
        const int excl = cnt[t] - x;
        cur[t] = excl;
        const int d = b * 128 + t;
        if (d < n) {
            row_ptr[d] = lo + excl;
            atomicAdd(&hcnt[127 - min(x, 127)], 1);
        }
    }
    if (b == 0 && t == 0) row_ptr[n] = etot;
    __syncthreads();
    if (t < 128 && hcnt[t]) atomicAdd(&dbin[t], hcnt[t]);
    for (int e = lo + t; e < hi; e += 256) {
        const int p = pairs[e];
        const int pos = atomicAdd(&cur[(p >> 24) & 127], 1);
        csr_src[lo + pos] = p & 0xFFFFFF;
    }
}

// ---- global degree order: local scan of dbin + zeroed global cursor ----
__global__ __launch_bounds__(256) void deg_scatter2_k(
    const int* __restrict__ row_ptr, const int* __restrict__ dbin,
    int* __restrict__ dcur, int* __restrict__ order, int n) {
    __shared__ int excl[128], red[128];
    __shared__ int h[128], gbase[128], lcur[128];
    const int t = threadIdx.x;
    if (t < 128) red[t] = dbin[t];
    __syncthreads();
#pragma unroll
    for (int s = 1; s < 128; s <<= 1) {
        const int add = (t < 128 && t >= s) ? red[t - s] : 0;
        __syncthreads();
        if (t < 128) red[t] += add;
        __syncthreads();
    }
    if (t < 128) {
        excl[t] = red[t] - dbin[t];
        h[t] = 0;
        lcur[t] = 0;
    }
    __syncthreads();
    const int d = blockIdx.x * 256 + t;
    int bin = -1;
    if (d < n) {
        const int deg = row_ptr[d + 1] - row_ptr[d];
        bin = 127 - min(deg, 127);
        atomicAdd(&h[bin], 1);
    }
    __syncthreads();
    if (t < 128) gbase[t] = h[t] ? (excl[t] + atomicAdd(&dcur[t], h[t])) : 0;
    __syncthreads();
    if (d < n) {
        const int p = atomicAdd(&lcur[bin], 1);
        order[gbase[bin] + p] = d;
    }
}

// ---------- layer-2 MFMA GEMM: 32 rows/block, wave = (slab,rowhalf) ----------
__global__ __launch_bounds__(256) void gemm2_k(
    const ush* __restrict__ ahi, const ush* __restrict__ alo,
    const ush* __restrict__ whl, const ush* __restrict__ wll,
    const ush* __restrict__ whr, const ush* __restrict__ wlr,
    ush* __restrict__ ybf, float* __restrict__ yf, int n) {
    const int l = threadIdx.x & 63;
    const int w = threadIdx.x >> 6;
    const int slab = w >> 1, rh = w & 1;
    const int r0 = blockIdx.x * 32 + rh * 16;
    const int arow = min(r0 + (l & 15), n - 1);
    const int kb = (l >> 4) * 8;
    bf16x8 ah[4], al[4];
#pragma unroll
    for (int ks = 0; ks < 4; ++ks) {
        ah[ks] = *reinterpret_cast<const bf16x8*>(ahi + (size_t)arow * 128 + ks * 32 + kb);
        al[ks] = *reinterpret_cast<const bf16x8*>(alo + (size_t)arow * 128 + ks * 32 + kb);
    }
    const ush* __restrict__ wh = slab ? whr : whl;
    const ush* __restrict__ wl = slab ? wlr : wll;
    const int drow = (l >> 4) * 4;
    const int dcol = l & 15;
    f32x4 acc[4];
#pragma unroll
    for (int c16 = 0; c16 < 4; ++c16) acc[c16] = {0.f, 0.f, 0.f, 0.f};
#pragma unroll
    for (int ks = 0; ks < 4; ++ks) {
        bf16x8 bh[4], bl[4];
#pragma unroll
        for (int c16 = 0; c16 < 4; ++c16) {
            const int fid = ks * 4 + c16;
            bh[c16] = *reinterpret_cast<const bf16x8*>(wh + (size_t)(fid * 64 + l) * 8);
            bl[c16] = *reinterpret_cast<const bf16x8*>(wl + (size_t)(fid * 64 + l) * 8);
        }
#pragma unroll
        for (int c16 = 0; c16 < 4; ++c16)
            acc[c16] = __builtin_amdgcn_mfma_f32_16x16x32_bf16(ah[ks], bh[c16], acc[c16], 0, 0, 0);
#pragma unroll
        for (int c16 = 0; c16 < 4; ++c16)
            acc[c16] = __builtin_amdgcn_mfma_f32_16x16x32_bf16(al[ks], bh[c16], acc[c16], 0, 0, 0);
#pragma unroll
        for (int c16 = 0; c16 < 4; ++c16)
            acc[c16] = __builtin_amdgcn_mfma_f32_16x16x32_bf16(ah[ks], bl[c16], acc[c16], 0, 0, 0);
    }
#pragma unroll
    for (int c16 = 0; c16 < 4; ++c16) {
        const int cg = c16 * 16 + dcol;
#pragma unroll
        for (int q = 0; q < 4; ++q) {
            const int gr = r0 + drow + q;
            if (gr < n) {
                if (slab == 0) ybf[(size_t)gr * 64 + cg] = f2bf(acc[c16][q]);
                else           yf[(size_t)gr * 64 + cg] = acc[c16][q];
            }
        }
    }
}

// ---------- fused per-dst softmax aggregation, H=2 (128 cols, xl bf16) ----------
__global__ __launch_bounds__(256) void gat_dst2_k(
    const ush* __restrict__ xl, const float* __restrict__ xr,
    const int* __restrict__ row_ptr, const int* __restrict__ csr_src,
    const int* __restrict__ order, const float* __restrict__ att,
    const float* __restrict__ bias, ush* __restrict__ h1hi,
    ush* __restrict__ h1lo, int n) {
    const int lane = threadIdx.x & 63;
    const int g = lane >> 4, il = lane & 15;
    const int w = (blockIdx.x * blockDim.x + threadIdx.x) >> 6;
    if (w >= n) return;
    const int d = order[w];

    float xv[8], av[8];
    {
        const float4* xp = reinterpret_cast<const float4*>(xr + (size_t)d * 128 + il * 8);
        const float4* ap = reinterpret_cast<const float4*>(att + il * 8);
        const float4 x0 = xp[0], x1 = xp[1], a0 = ap[0], a1 = ap[1];
        xv[0]=x0.x; xv[1]=x0.y; xv[2]=x0.z; xv[3]=x0.w;
        xv[4]=x1.x; xv[5]=x1.y; xv[6]=x1.z; xv[7]=x1.w;
        av[0]=a0.x; av[1]=a0.y; av[2]=a0.z; av[3]=a0.w;
        av[4]=a1.x; av[5]=a1.y; av[6]=a1.z; av[7]=a1.w;
    }
    const int rp0 = row_ptr[d], rp1 = row_ptr[d + 1];

    float s = 0.f;
    float acc[8] = {0.f, 0.f, 0.f, 0.f, 0.f, 0.f, 0.f, 0.f};
    int i = rp0 + g;
    for (; i + 4 < rp1; i += 8) {
        const int s0 = csr_src[i];
        const int s1 = csr_src[i + 4];
        const ushx8 u0 = *reinterpret_cast<const ushx8*>(xl + (((size_t)(unsigned)s0) << 7) + il * 8);
        const ushx8 u1 = *reinterpret_cast<const ushx8*>(xl + (((size_t)(unsigned)s1) << 7) + il * 8);
        float f0[8], f1[8], p0 = 0.f, p1 = 0.f;
#pragma unroll
        for (int j = 0; j < 8; ++j) {
            f0[j] = bf2f((ush)u0[j]);
            const float v = f0[j] + xv[j];
            p0 = fmaf(av[j], fmaxf(v, 0.2f * v), p0);
        }
#pragma unroll
        for (int j = 0; j < 8; ++j) {
            f1[j] = bf2f((ush)u1[j]);
            const float v = f1[j] + xv[j];
            p1 = fmaf(av[j], fmaxf(v, 0.2f * v), p1);
        }
        p0 += __shfl_xor(p0, 4, 64); p0 += __shfl_xor(p0, 2, 64); p0 += __shfl_xor(p0, 1, 64);
        p1 += __shfl_xor(p1, 4, 64); p1 += __shfl_xor(p1, 2, 64); p1 += __shfl_xor(p1, 1, 64);
        const float w0 = __expf(p0), w1 = __expf(p1);
        s += w0 + w1;
#pragma unroll
        for (int j = 0; j < 8; ++j) acc[j] = fmaf(w0, f0[j], fmaf(w1, f1[j], acc[j]));
    }
    if (i < rp1) {
        const int s0 = csr_src[i];
        const ushx8 u0 = *reinterpret_cast<const ushx8*>(xl + (((size_t)(unsigned)s0) << 7) + il * 8);
        float f0[8], p0 = 0.f;
#pragma unroll
        for (int j = 0; j < 8; ++j) {
            f0[j] = bf2f((ush)u0[j]);
            const float v = f0[j] + xv[j];
            p0 = fmaf(av[j], fmaxf(v, 0.2f * v), p0);
        }
        p0 += __shfl_xor(p0, 4, 64); p0 += __shfl_xor(p0, 2, 64); p0 += __shfl_xor(p0, 1, 64);
        const float w0 = __expf(p0);
        s += w0;
#pragma unroll
        for (int j = 0; j < 8; ++j) acc[j] = fmaf(w0, f0[j], acc[j]);
    }
#pragma unroll
    for (int off = 16; off <= 32; off <<= 1) {
        s += __shfl_xor(s, off, 64);
#pragma unroll
        for (int j = 0; j < 8; ++j) acc[j] += __shfl_xor(acc[j], off, 64);
    }
    if (g == 0) {
        const float inv = 1.f / (s + 1e-16f);
        float bv[8];
        {
            const float4* bp = reinterpret_cast<const float4*>(bias + il * 8);
            const float4 b0 = bp[0], b1 = bp[1];
            bv[0]=b0.x; bv[1]=b0.y; bv[2]=b0.z; bv[3]=b0.w;
            bv[4]=b1.x; bv[5]=b1.y; bv[6]=b1.z; bv[7]=b1.w;
        }
        ushx8 hh, ll;
#pragma unroll
        for (int j = 0; j < 8; ++j) {
            const float o = fmaxf(fmaf(acc[j], inv, bv[j]), 0.f);
            const ush h = f2bf(o);
            hh[j] = h;
            ll[j] = f2bf(o - bf2f(h));
        }
        *reinterpret_cast<ushx8*>(h1hi + (size_t)d * 128 + il * 8) = hh;
        *reinterpret_cast<ushx8*>(h1lo + (size_t)d * 128 + il * 8) = ll;
    }
}

// ---------- fused per-dst softmax aggregation, H=1 (64 cols, xl bf16) ----------
__global__ __launch_bounds__(256) void gat_dst1_k(
    const ush* __restrict__ xl, const float* __restrict__ xr,
    const int* __restrict__ row_ptr, const int* __restrict__ csr_src,
    const int* __restrict__ order, const float* __restrict__ att,
    const float* __restrict__ bias, float* __restrict__ out, int n) {
    const int lane = threadIdx.x & 63;
    const int g = lane >> 3, il = lane & 7;
    const int w = (blockIdx.x * blockDim.x + threadIdx.x) >> 6;
    if (w >= n) return;
    const int d = order[w];

    float xv[8], av[8];
    {
        const float4* xp = reinterpret_cast<const float4*>(xr + (size_t)d * 64 + il * 8);
        const float4* ap = reinterpret_cast<const float4*>(att + il * 8);
        const float4 x0 = xp[0], x1 = xp[1], a0 = ap[0], a1 = ap[1];
        xv[0]=x0.x; xv[1]=x0.y; xv[2]=x0.z; xv[3]=x0.w;
        xv[4]=x1.x; xv[5]=x1.y; xv[6]=x1.z; xv[7]=x1.w;
        av[0]=a0.x; av[1]=a0.y; av[2]=a0.z; av[3]=a0.w;
        av[4]=a1.x; av[5]=a1.y; av[6]=a1.z; av[7]=a1.w;
    }
    const int rp0 = row_ptr[d], rp1 = row_ptr[d + 1];

    float s = 0.f;
    float acc[8] = {0.f, 0.f, 0.f, 0.f, 0.f, 0.f, 0.f, 0.f};
    int i = rp0 + g;
    for (; i + 8 < rp1; i += 16) {
        const int s0 = csr_src[i];
        const int s1 = csr_src[i + 8];
        const ushx8 u0 = *reinterpret_cast<const ushx8*>(xl + (((size_t)(unsigned)s0) << 6) + il * 8);
        const ushx8 u1 = *reinterpret_cast<const ushx8*>(xl + (((size_t)(unsigned)s1) << 6) + il * 8);
        float f0[8], f1[8], p0 = 0.f, p1 = 0.f;
#pragma unroll
        for (int j = 0; j < 8; ++j) {
            f0[j] = bf2f((ush)u0[j]);
            const float v = f0[j] + xv[j];
            p0 = fmaf(av[j], fmaxf(v, 0.2f * v), p0);
        }
#pragma unroll
        for (int j = 0; j < 8; ++j) {
            f1[j] = bf2f((ush)u1[j]);
            const float v = f1[j] + xv[j];
            p1 = fmaf(av[j], fmaxf(v, 0.2f * v), p1);
        }
        p0 += __shfl_xor(p0, 4, 64); p0 += __shfl_xor(p0, 2, 64); p0 += __shfl_xor(p0, 1, 64);
        p1 += __shfl_xor(p1, 4, 64); p1 += __shfl_xor(p1, 2, 64); p1 += __shfl_xor(p1, 1, 64);
        const float w0 = __expf(p0), w1 = __expf(p1);
        s += w0 + w1;
#pragma unroll
        for (int j = 0; j < 8; ++j) acc[j] = fmaf(w0, f0[j], fmaf(w1, f1[j], acc[j]));
    }
    if (i < rp1) {
        const int s0 = csr_src[i];
        const ushx8 u0 = *reinterpret_cast<const ushx8*>(xl + (((size_t)(unsigned)s0) << 6) + il * 8);
        float f0[8], p0 = 0.f;
#pragma unroll
        for (int j = 0; j < 8; ++j) {
            f0[j] = bf2f((ush)u0[j]);
            const float v = f0[j] + xv[j];
            p0 = fmaf(av[j], fmaxf(v, 0.2f * v), p0);
        }
        p0 += __shfl_xor(p0, 4, 64); p0 += __shfl_xor(p0, 2, 64); p0 += __shfl_xor(p0, 1, 64);
        const float w0 = __expf(p0);
        s += w0;
#pragma unroll
        for (int j = 0; j < 8; ++j) acc[j] = fmaf(w0, f0[j], acc[j]);
    }
#pragma unroll
    for (int off = 8; off <= 32; off <<= 1) {
        s += __shfl_xor(s, off, 64);
#pragma unroll
        for (int j = 0; j < 8; ++j) acc[j] += __shfl_xor(acc[j], off, 64);
    }
    if (g == 0) {
        const float inv = 1.f / (s + 1e-16f);
        float bv[8];
        {
            const float4* bp = reinterpret_cast<const float4*>(bias + il * 8);
            const float4 b0 = bp[0], b1 = bp[1];
            bv[0]=b0.x; bv[1]=b0.y; bv[2]=b0.z; bv[3]=b0.w;
            bv[4]=b1.x; bv[5]=b1.y; bv[6]=b1.z; bv[7]=b1.w;
        }
        float4 o0, o1;
        o0.x = fmaxf(fmaf(acc[0], inv, bv[0]), 0.f);
        o0.y = fmaxf(fmaf(acc[1], inv, bv[1]), 0.f);
        o0.z = fmaxf(fmaf(acc[2], inv, bv[2]), 0.f);
        o0.w = fmaxf(fmaf(acc[3], inv, bv[3]), 0.f);
        o1.x = fmaxf(fmaf(acc[4], inv, bv[4]), 0.f);
        o1.y = fmaxf(fmaf(acc[5], inv, bv[5]), 0.f);
        o1.z = fmaxf(fmaf(acc[6], inv, bv[6]), 0.f);
        o1.w = fmaxf(fmaf(acc[7], inv, bv[7]), 0.f);
        float4* op = reinterpret_cast<float4*>(out + (size_t)d * 64 + il * 8);
        op[0] = o0;
        op[1] = o1;
    }
}

extern "C" void kernel_launch(void* const* d_in, const int* in_sizes, int n_in,
                              void* d_out, int out_size, void* d_ws, size_t ws_size,
                              hipStream_t stream) {
    const float* x    = (const float*)d_in[0];
    const int*   ei   = (const int*)d_in[1];
    const float* Wl1  = (const float*)d_in[2];
    const float* Wr1  = (const float*)d_in[3];
    const float* att1 = (const float*)d_in[4];
    const float* b1   = (const float*)d_in[5];
    const float* Wl2  = (const float*)d_in[6];
    const float* Wr2  = (const float*)d_in[7];
    const float* att2 = (const float*)d_in[8];
    const float* b2   = (const float*)d_in[9];

    const int n    = in_sizes[0] / 128;   // 50000
    const int e0   = in_sizes[1] / 2;     // 800000
    const int etot = e0 + n;
    const int* srcs = ei;
    const int* dsts = ei + e0;

    float* ws = (float*)d_ws;
    ush*   h1hi = (ush*)ws;                        // n*128 ush
    ush*   h1lo = (ush*)(ws + (size_t)n * 64);     // n*128 ush
    ush*   xlbf = (ush*)(ws + (size_t)n * 128);    // n*128 ush
    float* xr   = ws + (size_t)n * 192;            // n*128 f32
    int* row_ptr = (int*)(ws + (size_t)n * 320);   // n+2
    int* ghist   = row_ptr + (n + 2);              // 512
    int* cur     = ghist + 512;                    // 512
    int* dbin    = cur + 512;                      // 128
    int* dcur    = dbin + 128;                     // 128
    int* order   = dcur + 128;                     // n
    int* csr_src = order + n;                      // etot
    int* pairs   = csr_src + etot;                 // etot (packed)
    ush* wph     = (ush*)(pairs + etot);           // 96*512 ush
    ush* wpl     = wph + 96 * 512;                 // 96*512 ush

    const int NB    = (n + 127) / 128;             // 391 <= 512
    const int NDB   = (n + 255) / 256;             // 196
    const int nblka = (etot + CHUNK - 1) / CHUNK;  // 104
    const int g1    = (n + 15) / 16;               // 3125
    const int g2    = (n + 31) / 32;               // 1563

    // 1) zero ghist + cur + dbin + dcur
    hipMemsetAsync(ghist, 0, 1280 * sizeof(int), stream);
    // 2) hist (256 blocks) + prep_w (24 blocks)
    fusedA_k<<<256 + 24, 256, 0, stream>>>(dsts, ghist, Wl1, Wr1, Wl2, Wr2,
                                           wph, wpl, e0, etot);
    // 3) semisort (104 blocks, 8192 edges each) + layer-1 GEMM (g1 blocks)
    fusedB_k<<<nblka + g1, 256, 0, stream>>>(
        srcs, dsts, ghist, cur, pairs, x,
        wph, wpl, wph + 32 * 512, wpl + 32 * 512, xlbf, xr,
        e0, etot, nblka, n);
    // 4) row_ptr + csr_src + global degree hist
    bucket_fill2_k<<<NB, 256, 0, stream>>>(pairs, ghist, row_ptr, csr_src,
                                           dbin, n, etot);
    // 5) global degree order (scan folded in)
    deg_scatter2_k<<<NDB, 256, 0, stream>>>(row_ptr, dbin, dcur, order, n);
    // 6) layer-1 attention
    gat_dst2_k<<<(n + 3) / 4, 256, 0, stream>>>(xlbf, xr, row_ptr, csr_src, order,
                                                att1, b1, h1hi, h1lo, n);
    // 7) layer-2 GEMM
    gemm2_k<<<g2, 256, 0, stream>>>(h1hi, h1lo, wph + 64 * 512, wpl + 64 * 512,
                                    wph + 80 * 512, wpl + 80 * 512, xlbf, xr, n);
    // 8) layer-2 attention
    gat_dst1_k<<<(n + 3) / 4, 256, 0, stream>>>(xlbf, xr, row_ptr, csr_src, order,
                                                att2, b2, (float*)d_out, n);
}